// Round 6
// baseline (683.016 us; speedup 1.0000x reference)
//
#include <hip/hip_runtime.h>
#include <cmath>

#define HH 32
#define TT 4096
#define BB 512

typedef float v2 __attribute__((ext_vector_type(2)));

constexpr float F_EPS  = 1e-10f;
constexpr float F_MINV = 1e-6f;
constexpr float F_L2E  = 1.44269504088896340736f;   // log2(e)
constexpr float F_LN2  = 0.69314718055994530942f;   // ln(2)
constexpr float TWO_PI = 6.28318530717958647693f;

// DPP row-rotate within 16-lane rows (VALU-speed cross-lane move).
template<int N>
__device__ __forceinline__ float ror16(float x) {
    return __int_as_float(__builtin_amdgcn_mov_dpp(
        __float_as_int(x), 0x120 + N, 0xF, 0xF, false));
}

// lane l gets lane (l^16)'s value (within each 32-lane half; chains independent).
__device__ __forceinline__ float swz_xor16(float x) {
    return __int_as_float(__builtin_amdgcn_ds_swizzle(__float_as_int(x), 0x401F));
}

__global__ __launch_bounds__(64, 1)
void hmm_dpp_kernel(const float* __restrict__ obs,
                    const float* __restrict__ tlog,
                    const float* __restrict__ ilog,
                    const float* __restrict__ emean,
                    const float* __restrict__ elvar,
                    float* __restrict__ alpha,
                    float* __restrict__ ll)
{
    __shared__ float sA[HH * HH];

    const int lane = threadIdx.x;
    const int j    = lane & 31;          // this lane's state
    const int r    = lane & 15;          // lane within 16-row
    const int h    = (lane >> 4) & 1;    // row parity within chain
    const int c    = lane >> 5;          // chain within wave
    const int b    = (int)blockIdx.x * 2 + c;

    // ---- transition softmax(+eps), rows built by lanes 0..31 ----
    if (lane < HH) {
        float rw[HH];
        #pragma unroll
        for (int k = 0; k < HH; ++k) rw[k] = tlog[lane * HH + k];
        float m = rw[0];
        #pragma unroll
        for (int k = 1; k < HH; ++k) m = fmaxf(m, rw[k]);
        float z = 0.f;
        #pragma unroll
        for (int k = 0; k < HH; ++k) { rw[k] = __expf(rw[k] - m); z += rw[k]; }
        float rz = 1.f / z;
        #pragma unroll
        for (int k = 0; k < HH; ++k) sA[lane * HH + k] = fmaf(rw[k], rz, F_EPS);
    }
    __syncthreads();

    // ---- probe DPP ror direction (robust to convention) ----
    const int dir = (ror16<1>((float)r) == (float)((r + 1) & 15)) ? 1 : -1;

    // ---- per-lane A coefficients in gathered-arrival order ----
    // gathered value m = v2( p[h*16 + rm], p[(1-h)*16 + rm] ), rm = (r + dir*m) & 15
    v2 AV[16];
    #pragma unroll
    for (int m = 0; m < 16; ++m) {
        const int rm = (r + dir * m) & 15;
        const int i0 = h * 16 + rm;
        const int i1 = (1 - h) * 16 + rm;
        AV[m] = v2{ sA[i0 * HH + j], sA[i1 * HH + j] };
    }

    // ---- initial distribution (log2 domain) ----
    float il2;
    {
        float m = ilog[0];
        #pragma unroll
        for (int k = 1; k < HH; ++k) m = fmaxf(m, ilog[k]);
        float z = 0.f;
        #pragma unroll
        for (int k = 0; k < HH; ++k) z += __expf(ilog[k] - m);
        il2 = __log2f(__expf(ilog[j] - m) / z + F_EPS);
    }

    // ---- emission constants (log2 domain) ----
    const float meanj = emean[j];
    const float varj  = __expf(elvar[j]) + F_MINV;
    const float c1j   = 0.5f * F_L2E / varj;
    const float c0j   = -0.5f * __logf(TWO_PI * varj) * F_L2E;

    const float* ob = obs + (size_t)b * TT;
    float*       ap = alpha + (size_t)b * TT * HH + j;

    float pp, off = 0.f;

    // ---- t = 0 ----
    {
        float o = ob[0];
        float d = o - meanj;
        float q0 = fmaf(d * d, -c1j, c0j);
        float a2 = il2 + q0;
        *ap = a2 * F_LN2; ap += HH;
        pp = __builtin_amdgcn_exp2f(a2);
    }

    // ---- emission pipeline: slot t&7 holds (q_t, e2_t); obuf slot t&3 holds ob[t+8..] ----
    float Qs[8], E2s[8];
    #pragma unroll
    for (int u = 0; u < 8; ++u) {
        float o = ob[1 + u];
        float d = o - meanj;
        float q = fmaf(d * d, -c1j, c0j);
        Qs[(1 + u) & 7]  = q;
        E2s[(1 + u) & 7] = __builtin_amdgcn_exp2f(q);
    }
    float obuf[4];
    obuf[1] = ob[9]; obuf[2] = ob[10]; obuf[3] = ob[11]; obuf[0] = ob[12];

#define HMM_STEP(U8_, U4_, RENORM_, PF_)                                        \
    {                                                                           \
        float px_ = swz_xor16(pp);                                              \
        v2 g0; g0.x = pp; g0.y = px_;                                           \
        v2 g1, g2, g3, g4, g5, g6, g7, g8, g9, g10, g11, g12, g13, g14, g15;    \
        g1.x  = ror16<1>(g0.x);  g1.y  = ror16<1>(g0.y);                        \
        g2.x  = ror16<2>(g0.x);  g2.y  = ror16<2>(g0.y);                        \
        g3.x  = ror16<2>(g1.x);  g3.y  = ror16<2>(g1.y);                        \
        g4.x  = ror16<4>(g0.x);  g4.y  = ror16<4>(g0.y);                        \
        g5.x  = ror16<4>(g1.x);  g5.y  = ror16<4>(g1.y);                        \
        g6.x  = ror16<4>(g2.x);  g6.y  = ror16<4>(g2.y);                        \
        g7.x  = ror16<4>(g3.x);  g7.y  = ror16<4>(g3.y);                        \
        g8.x  = ror16<8>(g0.x);  g8.y  = ror16<8>(g0.y);                        \
        g9.x  = ror16<8>(g1.x);  g9.y  = ror16<8>(g1.y);                        \
        g10.x = ror16<8>(g2.x);  g10.y = ror16<8>(g2.y);                        \
        g11.x = ror16<8>(g3.x);  g11.y = ror16<8>(g3.y);                        \
        g12.x = ror16<8>(g4.x);  g12.y = ror16<8>(g4.y);                        \
        g13.x = ror16<8>(g5.x);  g13.y = ror16<8>(g5.y);                        \
        g14.x = ror16<8>(g6.x);  g14.y = ror16<8>(g6.y);                        \
        g15.x = ror16<8>(g7.x);  g15.y = ror16<8>(g7.y);                        \
        v2 a0 = g0 * AV[0];                                                     \
        v2 a1 = g1 * AV[1];                                                     \
        v2 a2 = g2 * AV[2];                                                     \
        v2 a3 = g3 * AV[3];                                                     \
        a0 = __builtin_elementwise_fma(g4,  AV[4],  a0);                        \
        a1 = __builtin_elementwise_fma(g5,  AV[5],  a1);                        \
        a2 = __builtin_elementwise_fma(g6,  AV[6],  a2);                        \
        a3 = __builtin_elementwise_fma(g7,  AV[7],  a3);                        \
        a0 = __builtin_elementwise_fma(g8,  AV[8],  a0);                        \
        a1 = __builtin_elementwise_fma(g9,  AV[9],  a1);                        \
        a2 = __builtin_elementwise_fma(g10, AV[10], a2);                        \
        a3 = __builtin_elementwise_fma(g11, AV[11], a3);                        \
        a0 = __builtin_elementwise_fma(g12, AV[12], a0);                        \
        a1 = __builtin_elementwise_fma(g13, AV[13], a1);                        \
        a2 = __builtin_elementwise_fma(g14, AV[14], a2);                        \
        a3 = __builtin_elementwise_fma(g15, AV[15], a3);                        \
        v2 s01 = a0 + a1;                                                       \
        v2 s23 = a2 + a3;                                                       \
        v2 sv  = s01 + s23;                                                     \
        float s_ = sv.x + sv.y;                                                 \
        float e2v = E2s[(U8_)];                                                 \
        float qv  = Qs[(U8_)];                                                  \
        float np  = s_ * e2v;                                                   \
        float lg  = __builtin_amdgcn_logf(s_);                                  \
        *ap = (off + qv + lg) * F_LN2;                                          \
        ap += HH;                                                               \
        if (RENORM_) {                                                          \
            v2 h0 = __builtin_elementwise_max(g0,  g1);                         \
            v2 h1 = __builtin_elementwise_max(g2,  g3);                         \
            v2 h2 = __builtin_elementwise_max(g4,  g5);                         \
            v2 h3 = __builtin_elementwise_max(g6,  g7);                         \
            v2 h4 = __builtin_elementwise_max(g8,  g9);                         \
            v2 h5 = __builtin_elementwise_max(g10, g11);                        \
            v2 h6 = __builtin_elementwise_max(g12, g13);                        \
            v2 h7 = __builtin_elementwise_max(g14, g15);                        \
            v2 q0_ = __builtin_elementwise_max(h0, h1);                         \
            v2 q1_ = __builtin_elementwise_max(h2, h3);                         \
            v2 q2_ = __builtin_elementwise_max(h4, h5);                         \
            v2 q3_ = __builtin_elementwise_max(h6, h7);                         \
            v2 t0_ = __builtin_elementwise_max(q0_, q1_);                       \
            v2 t1_ = __builtin_elementwise_max(q2_, q3_);                       \
            v2 rv  = __builtin_elementwise_max(t0_, t1_);                       \
            float mx = fmaxf(rv.x, rv.y);                                       \
            int ee; frexpf(mx, &ee);                                            \
            np *= ldexpf(1.0f, -ee);                                            \
            off += (float)ee;                                                   \
        }                                                                       \
        pp = np;                                                                \
        {                                                                       \
            float o_ = obuf[(U4_)];                                             \
            float d_ = o_ - meanj;                                              \
            float nq = fmaf(d_ * d_, -c1j, c0j);                                \
            Qs[(U8_)]  = nq;                                                    \
            E2s[(U8_)] = __builtin_amdgcn_exp2f(nq);                            \
        }                                                                       \
        obuf[(U4_)] = ob[(PF_)];                                                \
    }

    // main: t = 1 .. 4080 (255 blocks of 16); phases depend only on k
    for (int blk = 0; blk < 255; ++blk) {
        const int t0 = 1 + blk * 16;
        #pragma unroll
        for (int k = 0; k < 16; ++k) {
            HMM_STEP(((1 + k) & 7), ((1 + k) & 3), (((1 + k) & 7) == 0), (t0 + k + 12));
        }
    }
    // epilogue: t = 4081 .. 4095 (prefetch index clamped; dead slots harmless)
    #pragma unroll
    for (int k = 0; k < 15; ++k) {
        const int t  = 4081 + k;
        const int pf = (4093 + k <= 4095) ? (4093 + k) : 4095;
        HMM_STEP((t & 7), (t & 3), ((t & 7) == 0), pf);
    }
#undef HMM_STEP

    // ---- log-likelihood: ln2 * (off + log2 sum_j p_j), reduce over 32 lanes ----
    float sfin = pp;
    sfin += __shfl_xor(sfin, 1, 32);
    sfin += __shfl_xor(sfin, 2, 32);
    sfin += __shfl_xor(sfin, 4, 32);
    sfin += __shfl_xor(sfin, 8, 32);
    sfin += __shfl_xor(sfin, 16, 32);
    if (j == 0) ll[b] = (off + __builtin_amdgcn_logf(sfin)) * F_LN2;
}

extern "C" void kernel_launch(void* const* d_in, const int* in_sizes, int n_in,
                              void* d_out, int out_size, void* d_ws, size_t ws_size,
                              hipStream_t stream)
{
    const float* obs = (const float*)d_in[0];
    const float* tl  = (const float*)d_in[1];
    const float* il  = (const float*)d_in[2];
    const float* em  = (const float*)d_in[3];
    const float* ev  = (const float*)d_in[4];
    float* alpha = (float*)d_out;
    float* ll    = alpha + (size_t)BB * TT * HH;
    hmm_dpp_kernel<<<BB / 2, 64, 0, stream>>>(obs, tl, il, em, ev, alpha, ll);
}

// Round 8
// 459.479 us; speedup vs baseline: 1.4865x; 1.4865x over previous
//
#include <hip/hip_runtime.h>
#include <cmath>

#define HH 32
#define TT 4096
#define BB 512

constexpr float F_EPS  = 1e-10f;
constexpr float F_MINV = 1e-6f;
constexpr float F_L2E  = 1.44269504088896340736f;   // log2(e)
constexpr float F_LN2  = 0.69314718055994530942f;   // ln(2)
constexpr float TWO_PI = 6.28318530717958647693f;

// DPP row-rotate within 16-lane rows (VALU-speed cross-lane move).
template<int N>
__device__ __forceinline__ float ror16(float x) {
    return __int_as_float(__builtin_amdgcn_mov_dpp(
        __float_as_int(x), 0x120 + N, 0xF, 0xF, false));
}

// Pair-combine with the ^16 / ^32 partner lane via gfx950 permlane swaps.
// Feeding the SAME value to both operands guarantees {out.x,out.y} =
// {own, partner} in some order for every lane, under any odd/even pairing
// convention -> sum/max are unconditionally correct. No probes needed.
#if __has_builtin(__builtin_amdgcn_permlane16_swap)
__device__ __forceinline__ float psum16(float a) {
    auto rr = __builtin_amdgcn_permlane16_swap(__float_as_uint(a), __float_as_uint(a), false, false);
    return __uint_as_float(rr[0]) + __uint_as_float(rr[1]);
}
#else
__device__ __forceinline__ float psum16(float a) {
    float x, y;
    asm volatile("v_mov_b32 %0, %2\n\tv_mov_b32 %1, %2\n\tv_permlane16_swap_b32 %0, %1"
                 : "=&v"(x), "=&v"(y) : "v"(a));
    return x + y;
}
#endif
#if __has_builtin(__builtin_amdgcn_permlane32_swap)
__device__ __forceinline__ float psum32(float a) {
    auto rr = __builtin_amdgcn_permlane32_swap(__float_as_uint(a), __float_as_uint(a), false, false);
    return __uint_as_float(rr[0]) + __uint_as_float(rr[1]);
}
__device__ __forceinline__ float pmax32(float a) {
    auto rr = __builtin_amdgcn_permlane32_swap(__float_as_uint(a), __float_as_uint(a), false, false);
    return fmaxf(__uint_as_float(rr[0]), __uint_as_float(rr[1]));
}
#else
__device__ __forceinline__ float psum32(float a) {
    float x, y;
    asm volatile("v_mov_b32 %0, %2\n\tv_mov_b32 %1, %2\n\tv_permlane32_swap_b32 %0, %1"
                 : "=&v"(x), "=&v"(y) : "v"(a));
    return x + y;
}
__device__ __forceinline__ float pmax32(float a) {
    float x, y;
    asm volatile("v_mov_b32 %0, %2\n\tv_mov_b32 %1, %2\n\tv_permlane32_swap_b32 %0, %1"
                 : "=&v"(x), "=&v"(y) : "v"(a));
    return fmaxf(x, y);
}
#endif

__global__ __launch_bounds__(64, 1)
void hmm_pl_kernel(const float* __restrict__ obs,
                   const float* __restrict__ tlog,
                   const float* __restrict__ ilog,
                   const float* __restrict__ emean,
                   const float* __restrict__ elvar,
                   float* __restrict__ alpha,
                   float* __restrict__ ll)
{
    __shared__ float sA[HH * HH];

    const int lane = threadIdx.x;
    const int r    = lane & 15;      // lane within 16-row
    const int qd   = lane >> 4;      // quarter 0..3
    const int b    = blockIdx.x;     // one chain per wave

    // ---- transition softmax(+eps), rows built by lanes 0..31 ----
    if (lane < HH) {
        float rw[HH];
        #pragma unroll
        for (int k = 0; k < HH; ++k) rw[k] = tlog[lane * HH + k];
        float m = rw[0];
        #pragma unroll
        for (int k = 1; k < HH; ++k) m = fmaxf(m, rw[k]);
        float z = 0.f;
        #pragma unroll
        for (int k = 0; k < HH; ++k) { rw[k] = __expf(rw[k] - m); z += rw[k]; }
        float rz = 1.f / z;
        #pragma unroll
        for (int k = 0; k < HH; ++k) sA[lane * HH + k] = fmaf(rw[k], rz, F_EPS);
    }
    __syncthreads();

    // ---- probe DPP ror direction (verified mechanism in round 6) ----
    const int dir = (ror16<1>((float)r) == (float)((r + 1) & 15)) ? 1 : -1;

    // Two-phase layout:
    //  α-steps (t odd):  lane holds p[jB], computes state jA over i-half (qd&1);
    //                    combine partner = lane^16 (permlane16 pair-sum).
    //  β-steps (t even): lane holds p[jA], computes state jB over i-half (qd>>1);
    //                    combine partner = lane^32 (permlane32 pair-sum).
    const int jA = ((qd >> 1) << 4) + r;
    const int jB = ((qd & 1) << 4) + r;

    // per-lane A coefficients in gathered-arrival order, per phase
    float AA[16], AB[16];
    #pragma unroll
    for (int m = 0; m < 16; ++m) {
        const int rm = (r + dir * m) & 15;
        AA[m] = sA[(((qd & 1) << 4) + rm) * HH + jA];   // α: sum over i-half (qd&1), state jA
        AB[m] = sA[(((qd >> 1) << 4) + rm) * HH + jB];  // β: sum over i-half (qd>>1), state jB
    }

    // ---- initial distribution (log2 domain) for held state jB ----
    float il2B;
    {
        float m = ilog[0];
        #pragma unroll
        for (int k = 1; k < HH; ++k) m = fmaxf(m, ilog[k]);
        float z = 0.f;
        #pragma unroll
        for (int k = 0; k < HH; ++k) z += __expf(ilog[k] - m);
        il2B = __log2f(__expf(ilog[jB] - m) / z + F_EPS);
    }

    // ---- emission constants (log2 domain) for both per-lane states ----
    const float meanA = emean[jA], meanB = emean[jB];
    const float varA  = __expf(elvar[jA]) + F_MINV;
    const float varB  = __expf(elvar[jB]) + F_MINV;
    const float c1A   = 0.5f * F_L2E / varA, c1B = 0.5f * F_L2E / varB;
    const float c0A   = -0.5f * __logf(TWO_PI * varA) * F_L2E;
    const float c0B   = -0.5f * __logf(TWO_PI * varB) * F_L2E;

    const float* ob  = obs + (size_t)b * TT;
    float* apA = alpha + (size_t)b * TT * HH + HH + jA;   // t=1 base, α stores
    float* apB = alpha + (size_t)b * TT * HH + HH + jB;   // β stores

    float pp, off = 0.f;

    // ---- t = 0: lane holds p0[jB] ----
    {
        float o  = ob[0];
        float d  = o - meanB;
        float q0 = fmaf(d * d, -c1B, c0B);
        float a2 = il2B + q0;
        alpha[(size_t)b * TT * HH + jB] = a2 * F_LN2;
        pp = __builtin_amdgcn_exp2f(a2);
    }

    // ---- emission pipeline: slot t&7 holds (q_t, e2_t); parity fixed per slot ----
    float Qs[8], E2s[8];
    #pragma unroll
    for (int u = 0; u < 8; ++u) {
        const int t = 1 + u;
        float o   = ob[t];
        float mn  = (t & 1) ? meanA : meanB;
        float cc1 = (t & 1) ? c1A : c1B;
        float cc0 = (t & 1) ? c0A : c0B;
        float d   = o - mn;
        float qe  = fmaf(d * d, -cc1, cc0);
        Qs[t & 7]  = qe;
        E2s[t & 7] = __builtin_amdgcn_exp2f(qe);
    }
    float obuf[4];
    obuf[1] = ob[9]; obuf[2] = ob[10]; obuf[3] = ob[11]; obuf[0] = ob[12];
    const float* obp = ob + 13;   // obp[k] = ob[t0 + k + 12] with t0 = 1 + 16*blk

#define HMM_STEP(AC_, MEAN_, C1_, C0_, AP_, PSUM_, K_, U8_, U4_, RENORM_, PFI_)  \
    {                                                                           \
        float g1  = ror16<1>(pp),  g2  = ror16<2>(pp),  g3  = ror16<3>(pp);     \
        float g4  = ror16<4>(pp),  g5  = ror16<5>(pp),  g6  = ror16<6>(pp);     \
        float g7  = ror16<7>(pp),  g8  = ror16<8>(pp),  g9  = ror16<9>(pp);     \
        float g10 = ror16<10>(pp), g11 = ror16<11>(pp), g12 = ror16<12>(pp);    \
        float g13 = ror16<13>(pp), g14 = ror16<14>(pp), g15 = ror16<15>(pp);    \
        float a0 = pp * AC_[0];                                                 \
        float a1 = g1 * AC_[1];                                                 \
        float a2 = g2 * AC_[2];                                                 \
        float a3 = g3 * AC_[3];                                                 \
        a0 = fmaf(g4,  AC_[4],  a0);  a1 = fmaf(g5,  AC_[5],  a1);              \
        a2 = fmaf(g6,  AC_[6],  a2);  a3 = fmaf(g7,  AC_[7],  a3);              \
        a0 = fmaf(g8,  AC_[8],  a0);  a1 = fmaf(g9,  AC_[9],  a1);              \
        a2 = fmaf(g10, AC_[10], a2);  a3 = fmaf(g11, AC_[11], a3);              \
        a0 = fmaf(g12, AC_[12], a0);  a1 = fmaf(g13, AC_[13], a1);              \
        a2 = fmaf(g14, AC_[14], a2);  a3 = fmaf(g15, AC_[15], a3);              \
        float part = (a0 + a1) + (a2 + a3);                                     \
        float s_ = PSUM_(part);                                                 \
        float e2v = E2s[(U8_)];                                                 \
        float qv  = Qs[(U8_)];                                                  \
        float np  = s_ * e2v;                                                   \
        float lg  = __builtin_amdgcn_logf(s_);                                  \
        AP_[(size_t)(K_) * HH] = (off + qv + lg) * F_LN2;                       \
        if (RENORM_) {  /* only at β-steps: cross-half via pmax32 */            \
            float m0 = fmaxf(pp,  g1),  m1 = fmaxf(g2,  g3);                    \
            float m2 = fmaxf(g4,  g5),  m3 = fmaxf(g6,  g7);                    \
            float m4 = fmaxf(g8,  g9),  m5 = fmaxf(g10, g11);                   \
            float m6 = fmaxf(g12, g13), m7 = fmaxf(g14, g15);                   \
            float n0 = fmaxf(m0, m1), n1 = fmaxf(m2, m3);                       \
            float n2 = fmaxf(m4, m5), n3 = fmaxf(m6, m7);                       \
            float rmax = fmaxf(fmaxf(n0, n1), fmaxf(n2, n3));                   \
            float gmax = pmax32(rmax);                                          \
            int ee; frexpf(gmax, &ee);                                          \
            np *= ldexpf(1.0f, -ee);                                            \
            off += (float)ee;                                                   \
        }                                                                       \
        pp = np;                                                                \
        {                                                                       \
            float o_ = obuf[(U4_)];                                             \
            float d_ = o_ - (MEAN_);                                            \
            float nq = fmaf(d_ * d_, -(C1_), (C0_));                            \
            Qs[(U8_)]  = nq;                                                    \
            E2s[(U8_)] = __builtin_amdgcn_exp2f(nq);                            \
        }                                                                       \
        obuf[(U4_)] = obp[(PFI_)];                                              \
    }

    // main: t = 1 .. 4080 (255 blocks of 16); k even → t odd → α
    for (int blk = 0; blk < 255; ++blk) {
        #pragma unroll
        for (int kk = 0; kk < 8; ++kk) {
            const int k0 = 2 * kk;
            const int k1 = 2 * kk + 1;
            HMM_STEP(AA, meanA, c1A, c0A, apA, psum16,
                     k0, ((1 + k0) & 7), ((1 + k0) & 3), false, k0);
            HMM_STEP(AB, meanB, c1B, c0B, apB, psum32,
                     k1, ((1 + k1) & 7), ((1 + k1) & 3), (((1 + k1) & 7) == 0), k1);
        }
        apA += 16 * HH; apB += 16 * HH; obp += 16;
    }

    // epilogue: t = 4081 .. 4095 (15 steps; prefetch clamped to ob[4095])
    #pragma unroll
    for (int kk = 0; kk < 7; ++kk) {
        const int k0 = 2 * kk;
        const int k1 = 2 * kk + 1;
        HMM_STEP(AA, meanA, c1A, c0A, apA, psum16,
                 k0, ((1 + k0) & 7), ((1 + k0) & 3), false, (k0 <= 2 ? k0 : 2));
        HMM_STEP(AB, meanB, c1B, c0B, apB, psum32,
                 k1, ((1 + k1) & 7), ((1 + k1) & 3), (((1 + k1) & 7) == 0), (k1 <= 2 ? k1 : 2));
    }
    HMM_STEP(AA, meanA, c1A, c0A, apA, psum16,
             14, ((1 + 14) & 7), ((1 + 14) & 3), false, 2);
#undef HMM_STEP

    // ---- log-likelihood: row-sum (16) then cross-half pair-sum ----
    float ssum = pp;
    ssum += ror16<1>(pp);  ssum += ror16<2>(pp);  ssum += ror16<3>(pp);
    ssum += ror16<4>(pp);  ssum += ror16<5>(pp);  ssum += ror16<6>(pp);
    ssum += ror16<7>(pp);  ssum += ror16<8>(pp);  ssum += ror16<9>(pp);
    ssum += ror16<10>(pp); ssum += ror16<11>(pp); ssum += ror16<12>(pp);
    ssum += ror16<13>(pp); ssum += ror16<14>(pp); ssum += ror16<15>(pp);
    float stot = psum32(ssum);
    if (lane == 0) ll[b] = (off + __builtin_amdgcn_logf(stot)) * F_LN2;
}

extern "C" void kernel_launch(void* const* d_in, const int* in_sizes, int n_in,
                              void* d_out, int out_size, void* d_ws, size_t ws_size,
                              hipStream_t stream)
{
    const float* obs = (const float*)d_in[0];
    const float* tl  = (const float*)d_in[1];
    const float* il  = (const float*)d_in[2];
    const float* em  = (const float*)d_in[3];
    const float* ev  = (const float*)d_in[4];
    float* alpha = (float*)d_out;
    float* ll    = alpha + (size_t)BB * TT * HH;
    hmm_pl_kernel<<<BB, 64, 0, stream>>>(obs, tl, il, em, ev, alpha, ll);
}

// Round 10
// 412.943 us; speedup vs baseline: 1.6540x; 1.1127x over previous
//
#include <hip/hip_runtime.h>
#include <cmath>

#define HH 32
#define TT 4096
#define BB 512

typedef float f4 __attribute__((ext_vector_type(4), aligned(4)));

constexpr float F_EPS  = 1e-10f;
constexpr float F_MINV = 1e-6f;
constexpr float F_L2E  = 1.44269504088896340736f;   // log2(e)
constexpr float F_LN2  = 0.69314718055994530942f;   // ln(2)
constexpr float TWO_PI = 6.28318530717958647693f;

// DPP row-rotate within 16-lane rows (VALU-speed cross-lane move).
template<int N>
__device__ __forceinline__ float ror16(float x) {
    return __int_as_float(__builtin_amdgcn_mov_dpp(
        __float_as_int(x), 0x120 + N, 0xF, 0xF, false));
}

// Pair-combine with the ^16 / ^32 partner lane via gfx950 permlane swaps.
// Feeding the SAME value to both operands guarantees {out.x,out.y} =
// {own, partner} in some order for every lane -> sum/max unconditionally
// correct under any odd/even pairing convention. (Verified round 8.)
#if __has_builtin(__builtin_amdgcn_permlane16_swap)
__device__ __forceinline__ float psum16(float a) {
    auto rr = __builtin_amdgcn_permlane16_swap(__float_as_uint(a), __float_as_uint(a), false, false);
    return __uint_as_float(rr[0]) + __uint_as_float(rr[1]);
}
#else
__device__ __forceinline__ float psum16(float a) {
    float x, y;
    asm volatile("v_mov_b32 %0, %2\n\tv_mov_b32 %1, %2\n\tv_permlane16_swap_b32 %0, %1"
                 : "=&v"(x), "=&v"(y) : "v"(a));
    return x + y;
}
#endif
#if __has_builtin(__builtin_amdgcn_permlane32_swap)
__device__ __forceinline__ float psum32(float a) {
    auto rr = __builtin_amdgcn_permlane32_swap(__float_as_uint(a), __float_as_uint(a), false, false);
    return __uint_as_float(rr[0]) + __uint_as_float(rr[1]);
}
__device__ __forceinline__ float pmax32(float a) {
    auto rr = __builtin_amdgcn_permlane32_swap(__float_as_uint(a), __float_as_uint(a), false, false);
    return fmaxf(__uint_as_float(rr[0]), __uint_as_float(rr[1]));
}
#else
__device__ __forceinline__ float psum32(float a) {
    float x, y;
    asm volatile("v_mov_b32 %0, %2\n\tv_mov_b32 %1, %2\n\tv_permlane32_swap_b32 %0, %1"
                 : "=&v"(x), "=&v"(y) : "v"(a));
    return x + y;
}
__device__ __forceinline__ float pmax32(float a) {
    float x, y;
    asm volatile("v_mov_b32 %0, %2\n\tv_mov_b32 %1, %2\n\tv_permlane32_swap_b32 %0, %1"
                 : "=&v"(x), "=&v"(y) : "v"(a));
    return fmaxf(x, y);
}
#endif

__global__ __launch_bounds__(64, 1)
void hmm_pl2_kernel(const float* __restrict__ obs,
                    const float* __restrict__ tlog,
                    const float* __restrict__ ilog,
                    const float* __restrict__ emean,
                    const float* __restrict__ elvar,
                    float* __restrict__ alpha,
                    float* __restrict__ ll)
{
    __shared__ float sA[HH * HH];

    const int lane = threadIdx.x;
    const int r    = lane & 15;      // lane within 16-row
    const int qd   = lane >> 4;      // quarter 0..3
    const int b    = blockIdx.x;     // one chain per wave

    // ---- transition softmax(+eps), rows built by lanes 0..31 ----
    if (lane < HH) {
        float rw[HH];
        #pragma unroll
        for (int k = 0; k < HH; ++k) rw[k] = tlog[lane * HH + k];
        float m = rw[0];
        #pragma unroll
        for (int k = 1; k < HH; ++k) m = fmaxf(m, rw[k]);
        float z = 0.f;
        #pragma unroll
        for (int k = 0; k < HH; ++k) { rw[k] = __expf(rw[k] - m); z += rw[k]; }
        float rz = 1.f / z;
        #pragma unroll
        for (int k = 0; k < HH; ++k) sA[lane * HH + k] = fmaf(rw[k], rz, F_EPS);
    }
    __syncthreads();

    // ---- probe DPP ror direction (mechanism verified rounds 6-8) ----
    const int dir = (ror16<1>((float)r) == (float)((r + 1) & 15)) ? 1 : -1;

    // Two-phase layout (verified round 8):
    //  α (t odd):  lane holds p[jB], computes state jA over i-half (qd&1); combine ^16.
    //  β (t even): lane holds p[jA], computes state jB over i-half (qd>>1); combine ^32.
    const int jA = ((qd >> 1) << 4) + r;
    const int jB = ((qd & 1) << 4) + r;

    float AA[16], AB[16];
    #pragma unroll
    for (int m = 0; m < 16; ++m) {
        const int rm = (r + dir * m) & 15;
        AA[m] = sA[(((qd & 1) << 4) + rm) * HH + jA];
        AB[m] = sA[(((qd >> 1) << 4) + rm) * HH + jB];
    }

    // ---- initial distribution (log2 domain) for held state jB ----
    float il2B;
    {
        float m = ilog[0];
        #pragma unroll
        for (int k = 1; k < HH; ++k) m = fmaxf(m, ilog[k]);
        float z = 0.f;
        #pragma unroll
        for (int k = 0; k < HH; ++k) z += __expf(ilog[k] - m);
        il2B = __log2f(__expf(ilog[jB] - m) / z + F_EPS);
    }

    // ---- emission constants (log2 domain) for both per-lane states ----
    const float meanA = emean[jA], meanB = emean[jB];
    const float varA  = __expf(elvar[jA]) + F_MINV;
    const float varB  = __expf(elvar[jB]) + F_MINV;
    const float c1A   = 0.5f * F_L2E / varA, c1B = 0.5f * F_L2E / varB;
    const float c0A   = -0.5f * __logf(TWO_PI * varA) * F_L2E;
    const float c0B   = -0.5f * __logf(TWO_PI * varB) * F_L2E;

    const float* ob  = obs + (size_t)b * TT;
    float* apA = alpha + (size_t)b * TT * HH + HH + jA;   // t=1 base, α stores
    float* apB = alpha + (size_t)b * TT * HH + HH + jB;   // β stores

    float pp, off = 0.f;

    // ---- t = 0: lane holds p0[jB] ----
    {
        float o  = ob[0];
        float d  = o - meanB;
        float q0 = fmaf(d * d, -c1B, c0B);
        float a2 = il2B + q0;
        alpha[(size_t)b * TT * HH + jB] = a2 * F_LN2;
        pp = __builtin_amdgcn_exp2f(a2);
    }

    // ---- emission pipeline: slot t&7 holds (q_t, e2_t); parity fixed per slot ----
    float Qs[8], E2s[8];
    #pragma unroll
    for (int u = 0; u < 8; ++u) {
        const int t = 1 + u;
        float o   = ob[t];
        float mn  = (t & 1) ? meanA : meanB;
        float cc1 = (t & 1) ? c1A : c1B;
        float cc0 = (t & 1) ? c0A : c0B;
        float d   = o - mn;
        float qe  = fmaf(d * d, -cc1, cc0);
        Qs[t & 7]  = qe;
        E2s[t & 7] = __builtin_amdgcn_exp2f(qe);
    }

    // ---- double-buffered obs staging, 16-step lookahead ----
    // Block blk (t0 = 16*blk+1) consumes Rcur[k] = ob[t0+8+k] (k=0..15) for the
    // Q/E2 refill of time t0+k+8. Rnext for blk+1 is loaded at blk start.
    f4 RA[4], RB[4];
    {
        const f4* lp = (const f4*)(ob + 9);        // RA = ob[9..24] for blk 0
        RA[0] = lp[0]; RA[1] = lp[1]; RA[2] = lp[2]; RA[3] = lp[3];
    }

#define HMM_STEP(AC_, MEAN_, C1_, C0_, AP_, PSUM_, K_, U8_, RENORM_, OVAL_)     \
    {                                                                           \
        float g1  = ror16<1>(pp),  g2  = ror16<2>(pp),  g3  = ror16<3>(pp);     \
        float g4  = ror16<4>(pp),  g5  = ror16<5>(pp),  g6  = ror16<6>(pp);     \
        float g7  = ror16<7>(pp),  g8  = ror16<8>(pp),  g9  = ror16<9>(pp);     \
        float g10 = ror16<10>(pp), g11 = ror16<11>(pp), g12 = ror16<12>(pp);    \
        float g13 = ror16<13>(pp), g14 = ror16<14>(pp), g15 = ror16<15>(pp);    \
        float a0 = pp * AC_[0];                                                 \
        float a1 = g1 * AC_[1];                                                 \
        float a2 = g2 * AC_[2];                                                 \
        float a3 = g3 * AC_[3];                                                 \
        a0 = fmaf(g4,  AC_[4],  a0);  a1 = fmaf(g5,  AC_[5],  a1);              \
        a2 = fmaf(g6,  AC_[6],  a2);  a3 = fmaf(g7,  AC_[7],  a3);              \
        a0 = fmaf(g8,  AC_[8],  a0);  a1 = fmaf(g9,  AC_[9],  a1);              \
        a2 = fmaf(g10, AC_[10], a2);  a3 = fmaf(g11, AC_[11], a3);              \
        a0 = fmaf(g12, AC_[12], a0);  a1 = fmaf(g13, AC_[13], a1);              \
        a2 = fmaf(g14, AC_[14], a2);  a3 = fmaf(g15, AC_[15], a3);              \
        float part = (a0 + a1) + (a2 + a3);                                     \
        float s_ = PSUM_(part);                                                 \
        float e2v = E2s[(U8_)];                                                 \
        float qv  = Qs[(U8_)];                                                  \
        float np  = s_ * e2v;                                                   \
        float lg  = __builtin_amdgcn_logf(s_);                                  \
        AP_[(size_t)(K_) * HH] = (off + qv + lg) * F_LN2;                       \
        if (RENORM_) {  /* only at β-steps: cross-half via pmax32 */            \
            float m0 = fmaxf(pp,  g1),  m1 = fmaxf(g2,  g3);                    \
            float m2 = fmaxf(g4,  g5),  m3 = fmaxf(g6,  g7);                    \
            float m4 = fmaxf(g8,  g9),  m5 = fmaxf(g10, g11);                   \
            float m6 = fmaxf(g12, g13), m7 = fmaxf(g14, g15);                   \
            float n0 = fmaxf(m0, m1), n1 = fmaxf(m2, m3);                       \
            float n2 = fmaxf(m4, m5), n3 = fmaxf(m6, m7);                       \
            float rmax = fmaxf(fmaxf(n0, n1), fmaxf(n2, n3));                   \
            float gmax = pmax32(rmax);                                          \
            int ee; frexpf(gmax, &ee);                                          \
            np *= ldexpf(1.0f, -ee);                                            \
            off += (float)ee;                                                   \
        }                                                                       \
        pp = np;                                                                \
        {                                                                       \
            float o_ = (OVAL_);                                                 \
            float d_ = o_ - (MEAN_);                                            \
            float nq = fmaf(d_ * d_, -(C1_), (C0_));                            \
            Qs[(U8_)]  = nq;                                                    \
            E2s[(U8_)] = __builtin_amdgcn_exp2f(nq);                            \
        }                                                                       \
    }

    // One 16-step block: issue next-block loads, then 8 α/β pairs.
#define HMM_BLOCK(RC_, RN_, BASE_)                                              \
    {                                                                           \
        const f4* lp_ = (const f4*)(ob + (BASE_));                              \
        RN_[0] = lp_[0]; RN_[1] = lp_[1]; RN_[2] = lp_[2]; RN_[3] = lp_[3];     \
        _Pragma("unroll")                                                       \
        for (int kk = 0; kk < 8; ++kk) {                                        \
            const int k0 = 2 * kk;                                              \
            const int k1 = 2 * kk + 1;                                          \
            HMM_STEP(AA, meanA, c1A, c0A, apA, psum16,                          \
                     k0, ((1 + k0) & 7), false, RC_[k0 >> 2][k0 & 3]);          \
            HMM_STEP(AB, meanB, c1B, c0B, apB, psum32,                          \
                     k1, ((1 + k1) & 7), (((1 + k1) & 7) == 0),                 \
                     RC_[k1 >> 2][k1 & 3]);                                     \
        }                                                                       \
        apA += 16 * HH; apB += 16 * HH;                                         \
    }

    // main: blocks 0..253 (t = 1 .. 4064)
    for (int it = 0; it < 127; ++it) {
        HMM_BLOCK(RA, RB, 32 * it + 25);
        HMM_BLOCK(RB, RA, 32 * it + 41);
    }
    // blk 254 (t = 4065..4080); next-buffer base clamped in-bounds (dead values)
    HMM_BLOCK(RA, RB, 4080);

    // epilogue: t = 4081 .. 4095 (15 steps; refills dead, use RB)
    #pragma unroll
    for (int kk = 0; kk < 7; ++kk) {
        const int k0 = 2 * kk;
        const int k1 = 2 * kk + 1;
        HMM_STEP(AA, meanA, c1A, c0A, apA, psum16,
                 k0, ((1 + k0) & 7), false, RB[k0 >> 2][k0 & 3]);
        HMM_STEP(AB, meanB, c1B, c0B, apB, psum32,
                 k1, ((1 + k1) & 7), (((1 + k1) & 7) == 0), RB[k1 >> 2][k1 & 3]);
    }
    HMM_STEP(AA, meanA, c1A, c0A, apA, psum16,
             14, ((1 + 14) & 7), false, RB[3][2]);
#undef HMM_BLOCK
#undef HMM_STEP

    // ---- log-likelihood: row-sum (16) then cross-half pair-sum ----
    float ssum = pp;
    ssum += ror16<1>(pp);  ssum += ror16<2>(pp);  ssum += ror16<3>(pp);
    ssum += ror16<4>(pp);  ssum += ror16<5>(pp);  ssum += ror16<6>(pp);
    ssum += ror16<7>(pp);  ssum += ror16<8>(pp);  ssum += ror16<9>(pp);
    ssum += ror16<10>(pp); ssum += ror16<11>(pp); ssum += ror16<12>(pp);
    ssum += ror16<13>(pp); ssum += ror16<14>(pp); ssum += ror16<15>(pp);
    float stot = psum32(ssum);
    if (lane == 0) ll[b] = (off + __builtin_amdgcn_logf(stot)) * F_LN2;
}

extern "C" void kernel_launch(void* const* d_in, const int* in_sizes, int n_in,
                              void* d_out, int out_size, void* d_ws, size_t ws_size,
                              hipStream_t stream)
{
    const float* obs = (const float*)d_in[0];
    const float* tl  = (const float*)d_in[1];
    const float* il  = (const float*)d_in[2];
    const float* em  = (const float*)d_in[3];
    const float* ev  = (const float*)d_in[4];
    float* alpha = (float*)d_out;
    float* ll    = alpha + (size_t)BB * TT * HH;
    hmm_pl2_kernel<<<BB, 64, 0, stream>>>(obs, tl, il, em, ev, alpha, ll);
}

// Round 11
// 378.466 us; speedup vs baseline: 1.8047x; 1.0911x over previous
//
#include <hip/hip_runtime.h>
#include <cmath>

#define HH 32
#define TT 4096
#define BB 512
#define NCH 8           // chunks per chain
#define CL 512          // chunk length (NCH*CL == TT)
#define CW 256          // warmup steps (multiple of 32)
#define RST 40          // ws floats per (chain,chunk) record

typedef float f4 __attribute__((ext_vector_type(4), aligned(4)));

constexpr float F_EPS  = 1e-10f;
constexpr float F_MINV = 1e-6f;
constexpr float F_L2E  = 1.44269504088896340736f;   // log2(e)
constexpr float F_LN2  = 0.69314718055994530942f;   // ln(2)
constexpr float TWO_PI = 6.28318530717958647693f;

// DPP row-rotate within 16-lane rows.
template<int N>
__device__ __forceinline__ float ror16(float x) {
    return __int_as_float(__builtin_amdgcn_mov_dpp(
        __float_as_int(x), 0x120 + N, 0xF, 0xF, false));
}

// Pair-combine with ^16 / ^32 partner via gfx950 permlane swaps (verified r8/r10):
// feeding the SAME value to both operands gives {own, partner} in some order.
#if __has_builtin(__builtin_amdgcn_permlane16_swap)
__device__ __forceinline__ float psum16(float a) {
    auto rr = __builtin_amdgcn_permlane16_swap(__float_as_uint(a), __float_as_uint(a), false, false);
    return __uint_as_float(rr[0]) + __uint_as_float(rr[1]);
}
#else
__device__ __forceinline__ float psum16(float a) {
    float x, y;
    asm volatile("v_mov_b32 %0, %2\n\tv_mov_b32 %1, %2\n\tv_permlane16_swap_b32 %0, %1"
                 : "=&v"(x), "=&v"(y) : "v"(a));
    return x + y;
}
#endif
#if __has_builtin(__builtin_amdgcn_permlane32_swap)
__device__ __forceinline__ float psum32(float a) {
    auto rr = __builtin_amdgcn_permlane32_swap(__float_as_uint(a), __float_as_uint(a), false, false);
    return __uint_as_float(rr[0]) + __uint_as_float(rr[1]);
}
__device__ __forceinline__ float pmax32(float a) {
    auto rr = __builtin_amdgcn_permlane32_swap(__float_as_uint(a), __float_as_uint(a), false, false);
    return fmaxf(__uint_as_float(rr[0]), __uint_as_float(rr[1]));
}
#else
__device__ __forceinline__ float psum32(float a) {
    float x, y;
    asm volatile("v_mov_b32 %0, %2\n\tv_mov_b32 %1, %2\n\tv_permlane32_swap_b32 %0, %1"
                 : "=&v"(x), "=&v"(y) : "v"(a));
    return x + y;
}
__device__ __forceinline__ float pmax32(float a) {
    float x, y;
    asm volatile("v_mov_b32 %0, %2\n\tv_mov_b32 %1, %2\n\tv_permlane32_swap_b32 %0, %1"
                 : "=&v"(x), "=&v"(y) : "v"(a));
    return fmaxf(x, y);
}
#endif

// Shared per-kernel setup: transition softmax, DPP direction probe, two-phase
// A-coefficient arrays, emission constants. (Verified rounds 8/10.)
#define COMMON_SETUP                                                            \
    __shared__ float sA[HH * HH];                                               \
    const int lane = threadIdx.x;                                               \
    const int r    = lane & 15;                                                 \
    const int qd   = lane >> 4;                                                 \
    if (lane < HH) {                                                            \
        float rw[HH];                                                           \
        _Pragma("unroll")                                                       \
        for (int k = 0; k < HH; ++k) rw[k] = tlog[lane * HH + k];               \
        float m = rw[0];                                                        \
        _Pragma("unroll")                                                       \
        for (int k = 1; k < HH; ++k) m = fmaxf(m, rw[k]);                       \
        float z = 0.f;                                                          \
        _Pragma("unroll")                                                       \
        for (int k = 0; k < HH; ++k) { rw[k] = __expf(rw[k] - m); z += rw[k]; } \
        float rz = 1.f / z;                                                     \
        _Pragma("unroll")                                                       \
        for (int k = 0; k < HH; ++k) sA[lane * HH + k] = fmaf(rw[k], rz, F_EPS);\
    }                                                                           \
    __syncthreads();                                                            \
    const int dir = (ror16<1>((float)r) == (float)((r + 1) & 15)) ? 1 : -1;     \
    const int jA = ((qd >> 1) << 4) + r;                                        \
    const int jB = ((qd & 1) << 4) + r;                                         \
    float AA[16], AB[16];                                                       \
    _Pragma("unroll")                                                           \
    for (int m = 0; m < 16; ++m) {                                              \
        const int rm = (r + dir * m) & 15;                                      \
        AA[m] = sA[(((qd & 1) << 4) + rm) * HH + jA];                           \
        AB[m] = sA[(((qd >> 1) << 4) + rm) * HH + jB];                          \
    }                                                                           \
    const float meanA = emean[jA], meanB = emean[jB];                           \
    const float varA  = __expf(elvar[jA]) + F_MINV;                             \
    const float varB  = __expf(elvar[jB]) + F_MINV;                             \
    const float c1A   = 0.5f * F_L2E / varA, c1B = 0.5f * F_L2E / varB;         \
    const float c0A   = -0.5f * __logf(TWO_PI * varA) * F_L2E;                  \
    const float c0B   = -0.5f * __logf(TWO_PI * varB) * F_L2E;

#define IL2B_CALC(dst)                                                          \
    {                                                                           \
        float m = ilog[0];                                                      \
        _Pragma("unroll")                                                       \
        for (int k = 1; k < HH; ++k) m = fmaxf(m, ilog[k]);                     \
        float z = 0.f;                                                          \
        _Pragma("unroll")                                                       \
        for (int k = 0; k < HH; ++k) z += __expf(ilog[k] - m);                  \
        dst = __log2f(__expf(ilog[jB] - m) / z + F_EPS);                        \
    }

// Full-state sum in B-layout (after a beta step): row-sum then ^16 partner.
#define ROWSUM16(S_, P_)                                                        \
    float S_ = P_;                                                              \
    S_ += ror16<1>(P_);  S_ += ror16<2>(P_);  S_ += ror16<3>(P_);               \
    S_ += ror16<4>(P_);  S_ += ror16<5>(P_);  S_ += ror16<6>(P_);               \
    S_ += ror16<7>(P_);  S_ += ror16<8>(P_);  S_ += ror16<9>(P_);               \
    S_ += ror16<10>(P_); S_ += ror16<11>(P_); S_ += ror16<12>(P_);              \
    S_ += ror16<13>(P_); S_ += ror16<14>(P_); S_ += ror16<15>(P_);

// ======================= kernel 1: warmup + boundary measure =================
__global__ __launch_bounds__(64, 1)
void hmm_k1(const float* __restrict__ obs,
            const float* __restrict__ tlog,
            const float* __restrict__ ilog,
            const float* __restrict__ emean,
            const float* __restrict__ elvar,
            float* __restrict__ wsf)
{
    COMMON_SETUP
    const int bid = blockIdx.x;
    const int c   = bid >> 9;          // chunk 0..7
    const int b   = bid & 511;         // chain
    const int t0  = (c == 0) ? 0 : c * CL - CW;
    const float* ob  = obs + (size_t)b * TT;
    const float* obC = ob + t0;
    float* wrec = wsf + ((size_t)b * NCH + c) * RST;

    float pp, off = 0.f;
    if (c == 0) {
        float il2B; IL2B_CALC(il2B)
        float o = ob[0];
        float d = o - meanB;
        pp = __builtin_amdgcn_exp2f(il2B + fmaf(d * d, -c1B, c0B));
    } else {
        pp = 1.0f;                      // uniform start (direction converges)
    }

    float E2s[8];
    #pragma unroll
    for (int u = 0; u < 8; ++u) {
        const int t = 1 + u;            // local; abs parity == local parity
        float o   = obC[t];
        float mn  = (t & 1) ? meanA : meanB;
        float cc1 = (t & 1) ? c1A : c1B;
        float cc0 = (t & 1) ? c0A : c0B;
        float d   = o - mn;
        E2s[t & 7] = __builtin_amdgcn_exp2f(fmaf(d * d, -cc1, cc0));
    }
    f4 RA[4], RB[4];
    { const f4* lp = (const f4*)(obC + 9); RA[0]=lp[0]; RA[1]=lp[1]; RA[2]=lp[2]; RA[3]=lp[3]; }

#define K1_STEP(AC_, MEAN_, C1_, C0_, PSUM_, U8_, RENORM_, OVAL_)               \
    {                                                                           \
        float g1  = ror16<1>(pp),  g2  = ror16<2>(pp),  g3  = ror16<3>(pp);     \
        float g4  = ror16<4>(pp),  g5  = ror16<5>(pp),  g6  = ror16<6>(pp);     \
        float g7  = ror16<7>(pp),  g8  = ror16<8>(pp),  g9  = ror16<9>(pp);     \
        float g10 = ror16<10>(pp), g11 = ror16<11>(pp), g12 = ror16<12>(pp);    \
        float g13 = ror16<13>(pp), g14 = ror16<14>(pp), g15 = ror16<15>(pp);    \
        float a0 = pp * AC_[0];                                                 \
        float a1 = g1 * AC_[1];                                                 \
        float a2 = g2 * AC_[2];                                                 \
        float a3 = g3 * AC_[3];                                                 \
        a0 = fmaf(g4,  AC_[4],  a0);  a1 = fmaf(g5,  AC_[5],  a1);              \
        a2 = fmaf(g6,  AC_[6],  a2);  a3 = fmaf(g7,  AC_[7],  a3);              \
        a0 = fmaf(g8,  AC_[8],  a0);  a1 = fmaf(g9,  AC_[9],  a1);              \
        a2 = fmaf(g10, AC_[10], a2);  a3 = fmaf(g11, AC_[11], a3);              \
        a0 = fmaf(g12, AC_[12], a0);  a1 = fmaf(g13, AC_[13], a1);              \
        a2 = fmaf(g14, AC_[14], a2);  a3 = fmaf(g15, AC_[15], a3);              \
        float part = (a0 + a1) + (a2 + a3);                                     \
        float s_ = PSUM_(part);                                                 \
        float np = s_ * E2s[(U8_)];                                             \
        if (RENORM_) {  /* stale p is A-layout at beta steps -> pmax32 */       \
            float m0 = fmaxf(pp,  g1),  m1 = fmaxf(g2,  g3);                    \
            float m2 = fmaxf(g4,  g5),  m3 = fmaxf(g6,  g7);                    \
            float m4 = fmaxf(g8,  g9),  m5 = fmaxf(g10, g11);                   \
            float m6 = fmaxf(g12, g13), m7 = fmaxf(g14, g15);                   \
            float n0 = fmaxf(m0, m1), n1 = fmaxf(m2, m3);                       \
            float n2 = fmaxf(m4, m5), n3 = fmaxf(m6, m7);                       \
            float rmax = fmaxf(fmaxf(n0, n1), fmaxf(n2, n3));                   \
            float gmax = pmax32(rmax);                                          \
            int ee; frexpf(gmax, &ee);                                          \
            np *= ldexpf(1.0f, -ee);                                            \
            off += (float)ee;                                                   \
        }                                                                       \
        pp = np;                                                                \
        {                                                                       \
            float o_ = (OVAL_);                                                 \
            float d_ = o_ - (MEAN_);                                            \
            E2s[(U8_)] = __builtin_amdgcn_exp2f(fmaf(d_ * d_, -(C1_), (C0_)));  \
        }                                                                       \
    }

#define K1_BLOCK(RC_, RN_, BASE_)                                               \
    {                                                                           \
        const f4* lp_ = (const f4*)(obC + (BASE_));                             \
        RN_[0] = lp_[0]; RN_[1] = lp_[1]; RN_[2] = lp_[2]; RN_[3] = lp_[3];     \
        _Pragma("unroll")                                                       \
        for (int kk = 0; kk < 8; ++kk) {                                        \
            const int k0 = 2 * kk;                                              \
            const int k1 = 2 * kk + 1;                                          \
            K1_STEP(AA, meanA, c1A, c0A, psum16, ((1 + k0) & 7), false,         \
                    RC_[k0 >> 2][k0 & 3]);                                      \
            K1_STEP(AB, meanB, c1B, c0B, psum32, ((1 + k1) & 7),                \
                    (((1 + k1) & 7) == 0), RC_[k1 >> 2][k1 & 3]);               \
        }                                                                       \
    }

    const int NB1 = (c == 0) ? 0 : (CW / 32);      // warmup double-iterations
    const int NB2 = (c == 7) ? 0 : (CL / 32);      // traverse double-iterations

    for (int it = 0; it < NB1; ++it) {
        K1_BLOCK(RA, RB, 32 * it + 25);
        K1_BLOCK(RB, RA, 32 * it + 41);
    }
    // record 1: boundary t = c*CL (B-layout); pp, lambda_start, s_loc
    {
        ROWSUM16(rs, pp)
        float S  = psum16(rs);
        float l2 = __builtin_amdgcn_logf(S);
        if (lane < 32) wrec[jB] = pp;
        if (lane == 0) { wrec[32] = off + l2; wrec[34] = l2; }
    }
    for (int it = NB1; it < NB1 + NB2; ++it) {
        K1_BLOCK(RA, RB, 32 * it + 25);
        K1_BLOCK(RB, RA, 32 * it + 41);
    }
    if (c <= 6) {   // record 2: boundary t = (c+1)*CL; lambda_end
        ROWSUM16(rs, pp)
        float S = psum16(rs);
        if (lane == 0) wrec[33] = off + __builtin_amdgcn_logf(S);
    }
#undef K1_BLOCK
#undef K1_STEP
}

// ======================= kernel 3: corrected re-run + alpha ==================
__global__ __launch_bounds__(64, 1)
void hmm_k3(const float* __restrict__ obs,
            const float* __restrict__ tlog,
            const float* __restrict__ ilog,
            const float* __restrict__ emean,
            const float* __restrict__ elvar,
            const float* __restrict__ wsf,
            float* __restrict__ alpha,
            float* __restrict__ ll)
{
    COMMON_SETUP
    const int bid = blockIdx.x;
    const int c   = bid >> 9;
    const int b   = bid & 511;
    const int tS  = c * CL;                        // covers t = tS+1 .. min(tS+CL, TT-1)
    const float* ob  = obs + (size_t)b * TT;
    const float* obC = ob + tS;
    const size_t aBase = (size_t)b * TT * HH;
    const float* wrecB = wsf + (size_t)b * NCH * RST;

    float pp, off;
    if (c == 0) {
        float il2B; IL2B_CALC(il2B)
        float o  = ob[0];
        float d  = o - meanB;
        float a2 = il2B + fmaf(d * d, -c1B, c0B);
        alpha[aBase + jB] = a2 * F_LN2;            // t = 0
        pp  = __builtin_amdgcn_exp2f(a2);
        off = 0.f;
    } else {
        float T = wrecB[0 * RST + 33];             // true LSE2 at t = CL
        for (int cc = 1; cc < c; ++cc)
            T += wrecB[cc * RST + 33] - wrecB[cc * RST + 32];
        off = T - wrecB[c * RST + 34];             // true(c*CL) - s_loc_c
        pp  = wrecB[c * RST + jB];
    }

    float Qs[8], E2s[8];
    #pragma unroll
    for (int u = 0; u < 8; ++u) {
        const int t = 1 + u;
        float o   = obC[t];
        float mn  = (t & 1) ? meanA : meanB;
        float cc1 = (t & 1) ? c1A : c1B;
        float cc0 = (t & 1) ? c0A : c0B;
        float d   = o - mn;
        float qe  = fmaf(d * d, -cc1, cc0);
        Qs[t & 7]  = qe;
        E2s[t & 7] = __builtin_amdgcn_exp2f(qe);
    }
    f4 RA[4], RB[4];
    { const f4* lp = (const f4*)(obC + 9); RA[0]=lp[0]; RA[1]=lp[1]; RA[2]=lp[2]; RA[3]=lp[3]; }

    float* apA = alpha + aBase + (size_t)(tS + 1) * HH + jA;
    float* apB = alpha + aBase + (size_t)(tS + 1) * HH + jB;

#define K3_STEP(AC_, MEAN_, C1_, C0_, AP_, PSUM_, K_, U8_, RENORM_, OVAL_)      \
    {                                                                           \
        float g1  = ror16<1>(pp),  g2  = ror16<2>(pp),  g3  = ror16<3>(pp);     \
        float g4  = ror16<4>(pp),  g5  = ror16<5>(pp),  g6  = ror16<6>(pp);     \
        float g7  = ror16<7>(pp),  g8  = ror16<8>(pp),  g9  = ror16<9>(pp);     \
        float g10 = ror16<10>(pp), g11 = ror16<11>(pp), g12 = ror16<12>(pp);    \
        float g13 = ror16<13>(pp), g14 = ror16<14>(pp), g15 = ror16<15>(pp);    \
        float a0 = pp * AC_[0];                                                 \
        float a1 = g1 * AC_[1];                                                 \
        float a2 = g2 * AC_[2];                                                 \
        float a3 = g3 * AC_[3];                                                 \
        a0 = fmaf(g4,  AC_[4],  a0);  a1 = fmaf(g5,  AC_[5],  a1);              \
        a2 = fmaf(g6,  AC_[6],  a2);  a3 = fmaf(g7,  AC_[7],  a3);              \
        a0 = fmaf(g8,  AC_[8],  a0);  a1 = fmaf(g9,  AC_[9],  a1);              \
        a2 = fmaf(g10, AC_[10], a2);  a3 = fmaf(g11, AC_[11], a3);              \
        a0 = fmaf(g12, AC_[12], a0);  a1 = fmaf(g13, AC_[13], a1);              \
        a2 = fmaf(g14, AC_[14], a2);  a3 = fmaf(g15, AC_[15], a3);              \
        float part = (a0 + a1) + (a2 + a3);                                     \
        float s_ = PSUM_(part);                                                 \
        float e2v = E2s[(U8_)];                                                 \
        float qv  = Qs[(U8_)];                                                  \
        float np  = s_ * e2v;                                                   \
        float lg  = __builtin_amdgcn_logf(s_);                                  \
        AP_[(size_t)(K_) * HH] = (off + qv + lg) * F_LN2;                       \
        if (RENORM_) {                                                          \
            float m0 = fmaxf(pp,  g1),  m1 = fmaxf(g2,  g3);                    \
            float m2 = fmaxf(g4,  g5),  m3 = fmaxf(g6,  g7);                    \
            float m4 = fmaxf(g8,  g9),  m5 = fmaxf(g10, g11);                   \
            float m6 = fmaxf(g12, g13), m7 = fmaxf(g14, g15);                   \
            float n0 = fmaxf(m0, m1), n1 = fmaxf(m2, m3);                       \
            float n2 = fmaxf(m4, m5), n3 = fmaxf(m6, m7);                       \
            float rmax = fmaxf(fmaxf(n0, n1), fmaxf(n2, n3));                   \
            float gmax = pmax32(rmax);                                          \
            int ee; frexpf(gmax, &ee);                                          \
            np *= ldexpf(1.0f, -ee);                                            \
            off += (float)ee;                                                   \
        }                                                                       \
        pp = np;                                                                \
        {                                                                       \
            float o_ = (OVAL_);                                                 \
            float d_ = o_ - (MEAN_);                                            \
            float nq = fmaf(d_ * d_, -(C1_), (C0_));                            \
            Qs[(U8_)]  = nq;                                                    \
            E2s[(U8_)] = __builtin_amdgcn_exp2f(nq);                            \
        }                                                                       \
    }

#define K3_BLOCK(RC_, RN_, BASE_)                                               \
    {                                                                           \
        const f4* lp_ = (const f4*)(obC + (BASE_));                             \
        RN_[0] = lp_[0]; RN_[1] = lp_[1]; RN_[2] = lp_[2]; RN_[3] = lp_[3];     \
        _Pragma("unroll")                                                       \
        for (int kk = 0; kk < 8; ++kk) {                                        \
            const int k0 = 2 * kk;                                              \
            const int k1 = 2 * kk + 1;                                          \
            K3_STEP(AA, meanA, c1A, c0A, apA, psum16,                           \
                    k0, ((1 + k0) & 7), false, RC_[k0 >> 2][k0 & 3]);           \
            K3_STEP(AB, meanB, c1B, c0B, apB, psum32,                           \
                    k1, ((1 + k1) & 7), (((1 + k1) & 7) == 0),                  \
                    RC_[k1 >> 2][k1 & 3]);                                      \
        }                                                                       \
        apA += 16 * HH; apB += 16 * HH;                                         \
    }

    if (c < 7) {
        // 512 steps: t = tS+1 .. tS+512 (16 double-iterations)
        for (int it = 0; it < 16; ++it) {
            K3_BLOCK(RA, RB, 32 * it + 25);
            K3_BLOCK(RB, RA, 32 * it + 41);
        }
    } else {
        // 511 steps: t = 3585 .. 4095
        for (int it = 0; it < 15; ++it) {
            K3_BLOCK(RA, RB, 32 * it + 25);
            K3_BLOCK(RB, RA, 32 * it + 41);
        }
        // block t_local 481..496; load RB = obC[496..511] (abs 4080..4095, in-bounds)
        K3_BLOCK(RA, RB, 496);
        // epilogue t_local 497..511. Refill OVAL = obC[505+k] = RB[9+k] (tail fix).
        #pragma unroll
        for (int kk = 0; kk < 7; ++kk) {
            const int k0 = 2 * kk;
            const int k1 = 2 * kk + 1;
            const int m0 = (k0 + 9 <= 15) ? k0 + 9 : 15;
            const int m1 = (k1 + 9 <= 15) ? k1 + 9 : 15;
            K3_STEP(AA, meanA, c1A, c0A, apA, psum16,
                    k0, ((1 + k0) & 7), false, RB[m0 >> 2][m0 & 3]);
            K3_STEP(AB, meanB, c1B, c0B, apB, psum32,
                    k1, ((1 + k1) & 7), (((1 + k1) & 7) == 0), RB[m1 >> 2][m1 & 3]);
        }
        K3_STEP(AA, meanA, c1A, c0A, apA, psum16,
                14, ((1 + 14) & 7), false, RB[3][3]);
        // log-likelihood at t = 4095 (A-layout): row-sum then ^32 partner
        ROWSUM16(rs, pp)
        float stot = psum32(rs);
        if (lane == 0) ll[b] = (off + __builtin_amdgcn_logf(stot)) * F_LN2;
    }
#undef K3_BLOCK
#undef K3_STEP
}

extern "C" void kernel_launch(void* const* d_in, const int* in_sizes, int n_in,
                              void* d_out, int out_size, void* d_ws, size_t ws_size,
                              hipStream_t stream)
{
    const float* obs = (const float*)d_in[0];
    const float* tl  = (const float*)d_in[1];
    const float* il  = (const float*)d_in[2];
    const float* em  = (const float*)d_in[3];
    const float* ev  = (const float*)d_in[4];
    float* alpha = (float*)d_out;
    float* ll    = alpha + (size_t)BB * TT * HH;
    float* wsf   = (float*)d_ws;   // needs BB*NCH*RST*4 = 640 KB

    hmm_k1<<<BB * NCH, 64, 0, stream>>>(obs, tl, il, em, ev, wsf);
    hmm_k3<<<BB * NCH, 64, 0, stream>>>(obs, tl, il, em, ev, wsf, alpha, ll);
}

// Round 12
// 370.860 us; speedup vs baseline: 1.8417x; 1.0205x over previous
//
#include <hip/hip_runtime.h>
#include <cmath>

#define HH 32
#define TT 4096
#define BB 512
#define NCH 16          // chunks per chain
#define CL 256          // chunk length (NCH*CL == TT)
#define CW 128          // warmup steps (multiple of 32)
#define RST 40          // ws floats per (chain,chunk) record

typedef float f4 __attribute__((ext_vector_type(4), aligned(4)));

constexpr float F_EPS  = 1e-10f;
constexpr float F_MINV = 1e-6f;
constexpr float F_L2E  = 1.44269504088896340736f;   // log2(e)
constexpr float F_LN2  = 0.69314718055994530942f;   // ln(2)
constexpr float TWO_PI = 6.28318530717958647693f;

// DPP row-rotate within 16-lane rows.
template<int N>
__device__ __forceinline__ float ror16(float x) {
    return __int_as_float(__builtin_amdgcn_mov_dpp(
        __float_as_int(x), 0x120 + N, 0xF, 0xF, false));
}

// Pair-combine with ^16 / ^32 partner via gfx950 permlane swaps (verified r8-r11):
// feeding the SAME value to both operands gives {own, partner} in some order.
#if __has_builtin(__builtin_amdgcn_permlane16_swap)
__device__ __forceinline__ float psum16(float a) {
    auto rr = __builtin_amdgcn_permlane16_swap(__float_as_uint(a), __float_as_uint(a), false, false);
    return __uint_as_float(rr[0]) + __uint_as_float(rr[1]);
}
#else
__device__ __forceinline__ float psum16(float a) {
    float x, y;
    asm volatile("v_mov_b32 %0, %2\n\tv_mov_b32 %1, %2\n\tv_permlane16_swap_b32 %0, %1"
                 : "=&v"(x), "=&v"(y) : "v"(a));
    return x + y;
}
#endif
#if __has_builtin(__builtin_amdgcn_permlane32_swap)
__device__ __forceinline__ float psum32(float a) {
    auto rr = __builtin_amdgcn_permlane32_swap(__float_as_uint(a), __float_as_uint(a), false, false);
    return __uint_as_float(rr[0]) + __uint_as_float(rr[1]);
}
__device__ __forceinline__ float pmax32(float a) {
    auto rr = __builtin_amdgcn_permlane32_swap(__float_as_uint(a), __float_as_uint(a), false, false);
    return fmaxf(__uint_as_float(rr[0]), __uint_as_float(rr[1]));
}
#else
__device__ __forceinline__ float psum32(float a) {
    float x, y;
    asm volatile("v_mov_b32 %0, %2\n\tv_mov_b32 %1, %2\n\tv_permlane32_swap_b32 %0, %1"
                 : "=&v"(x), "=&v"(y) : "v"(a));
    return x + y;
}
__device__ __forceinline__ float pmax32(float a) {
    float x, y;
    asm volatile("v_mov_b32 %0, %2\n\tv_mov_b32 %1, %2\n\tv_permlane32_swap_b32 %0, %1"
                 : "=&v"(x), "=&v"(y) : "v"(a));
    return fmaxf(x, y);
}
#endif

// Shared per-kernel setup (verified rounds 8-11).
#define COMMON_SETUP                                                            \
    __shared__ float sA[HH * HH];                                               \
    const int lane = threadIdx.x;                                               \
    const int r    = lane & 15;                                                 \
    const int qd   = lane >> 4;                                                 \
    if (lane < HH) {                                                            \
        float rw[HH];                                                           \
        _Pragma("unroll")                                                       \
        for (int k = 0; k < HH; ++k) rw[k] = tlog[lane * HH + k];               \
        float m = rw[0];                                                        \
        _Pragma("unroll")                                                       \
        for (int k = 1; k < HH; ++k) m = fmaxf(m, rw[k]);                       \
        float z = 0.f;                                                          \
        _Pragma("unroll")                                                       \
        for (int k = 0; k < HH; ++k) { rw[k] = __expf(rw[k] - m); z += rw[k]; } \
        float rz = 1.f / z;                                                     \
        _Pragma("unroll")                                                       \
        for (int k = 0; k < HH; ++k) sA[lane * HH + k] = fmaf(rw[k], rz, F_EPS);\
    }                                                                           \
    __syncthreads();                                                            \
    const int dir = (ror16<1>((float)r) == (float)((r + 1) & 15)) ? 1 : -1;     \
    const int jA = ((qd >> 1) << 4) + r;                                        \
    const int jB = ((qd & 1) << 4) + r;                                         \
    float AA[16], AB[16];                                                       \
    _Pragma("unroll")                                                           \
    for (int m = 0; m < 16; ++m) {                                              \
        const int rm = (r + dir * m) & 15;                                      \
        AA[m] = sA[(((qd & 1) << 4) + rm) * HH + jA];                           \
        AB[m] = sA[(((qd >> 1) << 4) + rm) * HH + jB];                          \
    }                                                                           \
    const float meanA = emean[jA], meanB = emean[jB];                           \
    const float varA  = __expf(elvar[jA]) + F_MINV;                             \
    const float varB  = __expf(elvar[jB]) + F_MINV;                             \
    const float c1A   = 0.5f * F_L2E / varA, c1B = 0.5f * F_L2E / varB;         \
    const float c0A   = -0.5f * __logf(TWO_PI * varA) * F_L2E;                  \
    const float c0B   = -0.5f * __logf(TWO_PI * varB) * F_L2E;

#define IL2B_CALC(dst)                                                          \
    {                                                                           \
        float m = ilog[0];                                                      \
        _Pragma("unroll")                                                       \
        for (int k = 1; k < HH; ++k) m = fmaxf(m, ilog[k]);                     \
        float z = 0.f;                                                          \
        _Pragma("unroll")                                                       \
        for (int k = 0; k < HH; ++k) z += __expf(ilog[k] - m);                  \
        dst = __log2f(__expf(ilog[jB] - m) / z + F_EPS);                        \
    }

#define ROWSUM16(S_, P_)                                                        \
    float S_ = P_;                                                              \
    S_ += ror16<1>(P_);  S_ += ror16<2>(P_);  S_ += ror16<3>(P_);               \
    S_ += ror16<4>(P_);  S_ += ror16<5>(P_);  S_ += ror16<6>(P_);               \
    S_ += ror16<7>(P_);  S_ += ror16<8>(P_);  S_ += ror16<9>(P_);               \
    S_ += ror16<10>(P_); S_ += ror16<11>(P_); S_ += ror16<12>(P_);              \
    S_ += ror16<13>(P_); S_ += ror16<14>(P_); S_ += ror16<15>(P_);

// ======================= kernel 1: warmup + boundary measure =================
__global__ __launch_bounds__(64, 1)
void hmm_k1(const float* __restrict__ obs,
            const float* __restrict__ tlog,
            const float* __restrict__ ilog,
            const float* __restrict__ emean,
            const float* __restrict__ elvar,
            float* __restrict__ wsf)
{
    COMMON_SETUP
    const int bid = blockIdx.x;
    const int c   = bid >> 9;          // chunk 0..15
    const int b   = bid & 511;         // chain
    const int t0  = (c == 0) ? 0 : c * CL - CW;
    const float* ob  = obs + (size_t)b * TT;
    const float* obC = ob + t0;
    float* wrec = wsf + ((size_t)b * NCH + c) * RST;

    float pp, off = 0.f;
    if (c == 0) {
        float il2B; IL2B_CALC(il2B)
        float o = ob[0];
        float d = o - meanB;
        pp = __builtin_amdgcn_exp2f(il2B + fmaf(d * d, -c1B, c0B));
    } else {
        pp = 1.0f;                      // uniform start (direction converges)
    }

    float E2s[8];
    #pragma unroll
    for (int u = 0; u < 8; ++u) {
        const int t = 1 + u;            // local; abs parity == local parity (t0 even)
        float o   = obC[t];
        float mn  = (t & 1) ? meanA : meanB;
        float cc1 = (t & 1) ? c1A : c1B;
        float cc0 = (t & 1) ? c0A : c0B;
        float d   = o - mn;
        E2s[t & 7] = __builtin_amdgcn_exp2f(fmaf(d * d, -cc1, cc0));
    }
    f4 RA[4], RB[4];
    { const f4* lp = (const f4*)(obC + 9); RA[0]=lp[0]; RA[1]=lp[1]; RA[2]=lp[2]; RA[3]=lp[3]; }

#define K1_STEP(AC_, MEAN_, C1_, C0_, PSUM_, U8_, RENORM_, OVAL_)               \
    {                                                                           \
        float g1  = ror16<1>(pp),  g2  = ror16<2>(pp),  g3  = ror16<3>(pp);     \
        float g4  = ror16<4>(pp),  g5  = ror16<5>(pp),  g6  = ror16<6>(pp);     \
        float g7  = ror16<7>(pp),  g8  = ror16<8>(pp),  g9  = ror16<9>(pp);     \
        float g10 = ror16<10>(pp), g11 = ror16<11>(pp), g12 = ror16<12>(pp);    \
        float g13 = ror16<13>(pp), g14 = ror16<14>(pp), g15 = ror16<15>(pp);    \
        float a0 = pp * AC_[0];                                                 \
        float a1 = g1 * AC_[1];                                                 \
        float a2 = g2 * AC_[2];                                                 \
        float a3 = g3 * AC_[3];                                                 \
        a0 = fmaf(g4,  AC_[4],  a0);  a1 = fmaf(g5,  AC_[5],  a1);              \
        a2 = fmaf(g6,  AC_[6],  a2);  a3 = fmaf(g7,  AC_[7],  a3);              \
        a0 = fmaf(g8,  AC_[8],  a0);  a1 = fmaf(g9,  AC_[9],  a1);              \
        a2 = fmaf(g10, AC_[10], a2);  a3 = fmaf(g11, AC_[11], a3);              \
        a0 = fmaf(g12, AC_[12], a0);  a1 = fmaf(g13, AC_[13], a1);              \
        a2 = fmaf(g14, AC_[14], a2);  a3 = fmaf(g15, AC_[15], a3);              \
        float part = (a0 + a1) + (a2 + a3);                                     \
        float s_ = PSUM_(part);                                                 \
        float np = s_ * E2s[(U8_)];                                             \
        if (RENORM_) {                                                          \
            float m0 = fmaxf(pp,  g1),  m1 = fmaxf(g2,  g3);                    \
            float m2 = fmaxf(g4,  g5),  m3 = fmaxf(g6,  g7);                    \
            float m4 = fmaxf(g8,  g9),  m5 = fmaxf(g10, g11);                   \
            float m6 = fmaxf(g12, g13), m7 = fmaxf(g14, g15);                   \
            float n0 = fmaxf(m0, m1), n1 = fmaxf(m2, m3);                       \
            float n2 = fmaxf(m4, m5), n3 = fmaxf(m6, m7);                       \
            float rmax = fmaxf(fmaxf(n0, n1), fmaxf(n2, n3));                   \
            float gmax = pmax32(rmax);                                          \
            int ee; frexpf(gmax, &ee);                                          \
            np *= ldexpf(1.0f, -ee);                                            \
            off += (float)ee;                                                   \
        }                                                                       \
        pp = np;                                                                \
        {                                                                       \
            float o_ = (OVAL_);                                                 \
            float d_ = o_ - (MEAN_);                                            \
            E2s[(U8_)] = __builtin_amdgcn_exp2f(fmaf(d_ * d_, -(C1_), (C0_)));  \
        }                                                                       \
    }

#define K1_BLOCK(RC_, RN_, BASE_)                                               \
    {                                                                           \
        const f4* lp_ = (const f4*)(obC + (BASE_));                             \
        RN_[0] = lp_[0]; RN_[1] = lp_[1]; RN_[2] = lp_[2]; RN_[3] = lp_[3];     \
        _Pragma("unroll")                                                       \
        for (int kk = 0; kk < 8; ++kk) {                                        \
            const int k0 = 2 * kk;                                              \
            const int k1 = 2 * kk + 1;                                          \
            K1_STEP(AA, meanA, c1A, c0A, psum16, ((1 + k0) & 7), false,         \
                    RC_[k0 >> 2][k0 & 3]);                                      \
            K1_STEP(AB, meanB, c1B, c0B, psum32, ((1 + k1) & 7),                \
                    (((1 + k1) & 7) == 0), RC_[k1 >> 2][k1 & 3]);               \
        }                                                                       \
    }

    const int NB1 = (c == 0) ? 0 : (CW / 32);            // warmup double-iters
    const int NB2 = (c == NCH - 1) ? 0 : (CL / 32);      // traverse double-iters

    for (int it = 0; it < NB1; ++it) {
        K1_BLOCK(RA, RB, 32 * it + 25);
        K1_BLOCK(RB, RA, 32 * it + 41);
    }
    // record 1: boundary t = c*CL (B-layout); pp, lambda_start, s_loc
    {
        ROWSUM16(rs, pp)
        float S  = psum16(rs);
        float l2 = __builtin_amdgcn_logf(S);
        if (lane < 32) wrec[jB] = pp;
        if (lane == 0) { wrec[32] = off + l2; wrec[34] = l2; }
    }
    for (int it = NB1; it < NB1 + NB2; ++it) {
        K1_BLOCK(RA, RB, 32 * it + 25);
        K1_BLOCK(RB, RA, 32 * it + 41);
    }
    if (c < NCH - 1) {   // record 2: boundary t = (c+1)*CL; lambda_end
        ROWSUM16(rs, pp)
        float S = psum16(rs);
        if (lane == 0) wrec[33] = off + __builtin_amdgcn_logf(S);
    }
#undef K1_BLOCK
#undef K1_STEP
}

// ======================= kernel 3: corrected re-run + alpha ==================
__global__ __launch_bounds__(64, 1)
void hmm_k3(const float* __restrict__ obs,
            const float* __restrict__ tlog,
            const float* __restrict__ ilog,
            const float* __restrict__ emean,
            const float* __restrict__ elvar,
            const float* __restrict__ wsf,
            float* __restrict__ alpha,
            float* __restrict__ ll)
{
    COMMON_SETUP
    const int bid = blockIdx.x;
    const int c   = bid >> 9;
    const int b   = bid & 511;
    const int tS  = c * CL;                        // covers t = tS+1 .. min(tS+CL, TT-1)
    const float* ob  = obs + (size_t)b * TT;
    const float* obC = ob + tS;
    const size_t aBase = (size_t)b * TT * HH;
    const float* wrecB = wsf + (size_t)b * NCH * RST;

    float pp, off;
    if (c == 0) {
        float il2B; IL2B_CALC(il2B)
        float o  = ob[0];
        float d  = o - meanB;
        float a2 = il2B + fmaf(d * d, -c1B, c0B);
        alpha[aBase + jB] = a2 * F_LN2;            // t = 0
        pp  = __builtin_amdgcn_exp2f(a2);
        off = 0.f;
    } else {
        float T = wrecB[0 * RST + 33];             // true LSE2 at t = CL
        for (int cc = 1; cc < c; ++cc)
            T += wrecB[cc * RST + 33] - wrecB[cc * RST + 32];
        off = T - wrecB[c * RST + 34];             // true(c*CL) - s_loc_c
        pp  = wrecB[c * RST + jB];
    }

    float Qs[8], E2s[8];
    #pragma unroll
    for (int u = 0; u < 8; ++u) {
        const int t = 1 + u;
        float o   = obC[t];
        float mn  = (t & 1) ? meanA : meanB;
        float cc1 = (t & 1) ? c1A : c1B;
        float cc0 = (t & 1) ? c0A : c0B;
        float d   = o - mn;
        float qe  = fmaf(d * d, -cc1, cc0);
        Qs[t & 7]  = qe;
        E2s[t & 7] = __builtin_amdgcn_exp2f(qe);
    }
    f4 RA[4], RB[4];
    { const f4* lp = (const f4*)(obC + 9); RA[0]=lp[0]; RA[1]=lp[1]; RA[2]=lp[2]; RA[3]=lp[3]; }

    float* apA = alpha + aBase + (size_t)(tS + 1) * HH + jA;
    float* apB = alpha + aBase + (size_t)(tS + 1) * HH + jB;

#define K3_STEP(AC_, MEAN_, C1_, C0_, AP_, PSUM_, K_, U8_, RENORM_, OVAL_)      \
    {                                                                           \
        float g1  = ror16<1>(pp),  g2  = ror16<2>(pp),  g3  = ror16<3>(pp);     \
        float g4  = ror16<4>(pp),  g5  = ror16<5>(pp),  g6  = ror16<6>(pp);     \
        float g7  = ror16<7>(pp),  g8  = ror16<8>(pp),  g9  = ror16<9>(pp);     \
        float g10 = ror16<10>(pp), g11 = ror16<11>(pp), g12 = ror16<12>(pp);    \
        float g13 = ror16<13>(pp), g14 = ror16<14>(pp), g15 = ror16<15>(pp);    \
        float a0 = pp * AC_[0];                                                 \
        float a1 = g1 * AC_[1];                                                 \
        float a2 = g2 * AC_[2];                                                 \
        float a3 = g3 * AC_[3];                                                 \
        a0 = fmaf(g4,  AC_[4],  a0);  a1 = fmaf(g5,  AC_[5],  a1);              \
        a2 = fmaf(g6,  AC_[6],  a2);  a3 = fmaf(g7,  AC_[7],  a3);              \
        a0 = fmaf(g8,  AC_[8],  a0);  a1 = fmaf(g9,  AC_[9],  a1);              \
        a2 = fmaf(g10, AC_[10], a2);  a3 = fmaf(g11, AC_[11], a3);              \
        a0 = fmaf(g12, AC_[12], a0);  a1 = fmaf(g13, AC_[13], a1);              \
        a2 = fmaf(g14, AC_[14], a2);  a3 = fmaf(g15, AC_[15], a3);              \
        float part = (a0 + a1) + (a2 + a3);                                     \
        float s_ = PSUM_(part);                                                 \
        float e2v = E2s[(U8_)];                                                 \
        float qv  = Qs[(U8_)];                                                  \
        float np  = s_ * e2v;                                                   \
        float lg  = __builtin_amdgcn_logf(s_);                                  \
        AP_[(size_t)(K_) * HH] = (off + qv + lg) * F_LN2;                       \
        if (RENORM_) {                                                          \
            float m0 = fmaxf(pp,  g1),  m1 = fmaxf(g2,  g3);                    \
            float m2 = fmaxf(g4,  g5),  m3 = fmaxf(g6,  g7);                    \
            float m4 = fmaxf(g8,  g9),  m5 = fmaxf(g10, g11);                   \
            float m6 = fmaxf(g12, g13), m7 = fmaxf(g14, g15);                   \
            float n0 = fmaxf(m0, m1), n1 = fmaxf(m2, m3);                       \
            float n2 = fmaxf(m4, m5), n3 = fmaxf(m6, m7);                       \
            float rmax = fmaxf(fmaxf(n0, n1), fmaxf(n2, n3));                   \
            float gmax = pmax32(rmax);                                          \
            int ee; frexpf(gmax, &ee);                                          \
            np *= ldexpf(1.0f, -ee);                                            \
            off += (float)ee;                                                   \
        }                                                                       \
        pp = np;                                                                \
        {                                                                       \
            float o_ = (OVAL_);                                                 \
            float d_ = o_ - (MEAN_);                                            \
            float nq = fmaf(d_ * d_, -(C1_), (C0_));                            \
            Qs[(U8_)]  = nq;                                                    \
            E2s[(U8_)] = __builtin_amdgcn_exp2f(nq);                            \
        }                                                                       \
    }

#define K3_BLOCK(RC_, RN_, BASE_)                                               \
    {                                                                           \
        const f4* lp_ = (const f4*)(obC + (BASE_));                             \
        RN_[0] = lp_[0]; RN_[1] = lp_[1]; RN_[2] = lp_[2]; RN_[3] = lp_[3];     \
        _Pragma("unroll")                                                       \
        for (int kk = 0; kk < 8; ++kk) {                                        \
            const int k0 = 2 * kk;                                              \
            const int k1 = 2 * kk + 1;                                          \
            K3_STEP(AA, meanA, c1A, c0A, apA, psum16,                           \
                    k0, ((1 + k0) & 7), false, RC_[k0 >> 2][k0 & 3]);           \
            K3_STEP(AB, meanB, c1B, c0B, apB, psum32,                           \
                    k1, ((1 + k1) & 7), (((1 + k1) & 7) == 0),                  \
                    RC_[k1 >> 2][k1 & 3]);                                      \
        }                                                                       \
        apA += 16 * HH; apB += 16 * HH;                                         \
    }

    if (c < NCH - 1) {
        // 256 steps: t = tS+1 .. tS+256 (8 double-iterations)
        for (int it = 0; it < 8; ++it) {
            K3_BLOCK(RA, RB, 32 * it + 25);
            K3_BLOCK(RB, RA, 32 * it + 41);
        }
    } else {
        // 255 steps: t = 3841 .. 4095
        for (int it = 0; it < 7; ++it) {
            K3_BLOCK(RA, RB, 32 * it + 25);
            K3_BLOCK(RB, RA, 32 * it + 41);
        }
        // block t_local 225..240; load RB = obC[240..255] (abs 4080..4095)
        K3_BLOCK(RA, RB, 240);
        // epilogue t_local 241..255. Refill OVAL = obC[249+k] = RB[9+k] (clamped).
        #pragma unroll
        for (int kk = 0; kk < 7; ++kk) {
            const int k0 = 2 * kk;
            const int k1 = 2 * kk + 1;
            const int m0 = (k0 + 9 <= 15) ? k0 + 9 : 15;
            const int m1 = (k1 + 9 <= 15) ? k1 + 9 : 15;
            K3_STEP(AA, meanA, c1A, c0A, apA, psum16,
                    k0, ((1 + k0) & 7), false, RB[m0 >> 2][m0 & 3]);
            K3_STEP(AB, meanB, c1B, c0B, apB, psum32,
                    k1, ((1 + k1) & 7), (((1 + k1) & 7) == 0), RB[m1 >> 2][m1 & 3]);
        }
        K3_STEP(AA, meanA, c1A, c0A, apA, psum16,
                14, ((1 + 14) & 7), false, RB[3][3]);
        // log-likelihood at t = 4095 (A-layout): row-sum then ^32 partner
        ROWSUM16(rs, pp)
        float stot = psum32(rs);
        if (lane == 0) ll[b] = (off + __builtin_amdgcn_logf(stot)) * F_LN2;
    }
#undef K3_BLOCK
#undef K3_STEP
}

extern "C" void kernel_launch(void* const* d_in, const int* in_sizes, int n_in,
                              void* d_out, int out_size, void* d_ws, size_t ws_size,
                              hipStream_t stream)
{
    const float* obs = (const float*)d_in[0];
    const float* tl  = (const float*)d_in[1];
    const float* il  = (const float*)d_in[2];
    const float* em  = (const float*)d_in[3];
    const float* ev  = (const float*)d_in[4];
    float* alpha = (float*)d_out;
    float* ll    = alpha + (size_t)BB * TT * HH;
    float* wsf   = (float*)d_ws;   // needs BB*NCH*RST*4 = 1.31 MB

    hmm_k1<<<BB * NCH, 64, 0, stream>>>(obs, tl, il, em, ev, wsf);
    hmm_k3<<<BB * NCH, 64, 0, stream>>>(obs, tl, il, em, ev, wsf, alpha, ll);
}

// Round 13
// 102.832 us; speedup vs baseline: 6.6420x; 3.6065x over previous
//
#include <hip/hip_runtime.h>
#include <cmath>

#define HH 32
#define TT 4096
#define BB 512
#define NCH 64          // chunks per chain
#define CL  64          // chunk length (NCH*CL == TT)
#define CW  64          // warmup steps
#define RST 36          // ws floats per (chain,chunk) record (144 B, 16B-aligned)

typedef float  f4     __attribute__((ext_vector_type(4)));
typedef float  f32x4  __attribute__((ext_vector_type(4)));
typedef short  bf16x8 __attribute__((ext_vector_type(8)));
typedef unsigned int u32x4 __attribute__((ext_vector_type(4)));

constexpr float F_EPS  = 1e-10f;
constexpr float F_MINV = 1e-6f;
constexpr float F_L2E  = 1.44269504088896340736f;   // log2(e)
constexpr float F_LN2  = 0.69314718055994530942f;   // ln(2)
constexpr float TWO_PI = 6.28318530717958647693f;

// ---- pair-combine with ^16/^32 partner (verified r8-r12): same value into
// both operands -> {own, partner} in some order -> sum/max unconditional.
#if __has_builtin(__builtin_amdgcn_permlane16_swap)
__device__ __forceinline__ float psum16(float a) {
    auto rr = __builtin_amdgcn_permlane16_swap(__float_as_uint(a), __float_as_uint(a), false, false);
    return __uint_as_float(rr[0]) + __uint_as_float(rr[1]);
}
__device__ __forceinline__ float pmax16(float a) {
    auto rr = __builtin_amdgcn_permlane16_swap(__float_as_uint(a), __float_as_uint(a), false, false);
    return fmaxf(__uint_as_float(rr[0]), __uint_as_float(rr[1]));
}
#else
__device__ __forceinline__ float psum16(float a) {
    float x, y;
    asm volatile("v_mov_b32 %0, %2\n\tv_mov_b32 %1, %2\n\tv_permlane16_swap_b32 %0, %1"
                 : "=&v"(x), "=&v"(y) : "v"(a));
    return x + y;
}
__device__ __forceinline__ float pmax16(float a) {
    float x, y;
    asm volatile("v_mov_b32 %0, %2\n\tv_mov_b32 %1, %2\n\tv_permlane16_swap_b32 %0, %1"
                 : "=&v"(x), "=&v"(y) : "v"(a));
    return fmaxf(x, y);
}
#endif
#if __has_builtin(__builtin_amdgcn_permlane32_swap)
__device__ __forceinline__ float psum32(float a) {
    auto rr = __builtin_amdgcn_permlane32_swap(__float_as_uint(a), __float_as_uint(a), false, false);
    return __uint_as_float(rr[0]) + __uint_as_float(rr[1]);
}
__device__ __forceinline__ float pmax32(float a) {
    auto rr = __builtin_amdgcn_permlane32_swap(__float_as_uint(a), __float_as_uint(a), false, false);
    return fmaxf(__uint_as_float(rr[0]), __uint_as_float(rr[1]));
}
#else
__device__ __forceinline__ float psum32(float a) {
    float x, y;
    asm volatile("v_mov_b32 %0, %2\n\tv_mov_b32 %1, %2\n\tv_permlane32_swap_b32 %0, %1"
                 : "=&v"(x), "=&v"(y) : "v"(a));
    return x + y;
}
__device__ __forceinline__ float pmax32(float a) {
    float x, y;
    asm volatile("v_mov_b32 %0, %2\n\tv_mov_b32 %1, %2\n\tv_permlane32_swap_b32 %0, %1"
                 : "=&v"(x), "=&v"(y) : "v"(a));
    return fmaxf(x, y);
}
#endif

__device__ __forceinline__ unsigned short f2bf(float f) {   // RNE f32->bf16
    unsigned u = __float_as_uint(f);
    return (unsigned short)((u + 0x7FFFu + ((u >> 16) & 1u)) >> 16);
}
__device__ __forceinline__ unsigned cvtpk(float lo, float hi) {
    unsigned r;
    asm("v_cvt_pk_bf16_f32 %0, %1, %2" : "=v"(r) : "v"(lo), "v"(hi));
    return r;
}

// Per-lane setup shared by both kernels. Lane l: chain-col c16 = l&15,
// quarter g = l>>4. Lane's 8 states sig[e] = 4g+(e&3)+16*(e>>2) — both its
// D-fragment rows (tiles S0/S1) AND its B-operand k-slots (sigma folded into
// A' columns), so D feeds B with zero cross-lane movement.
#define MF_SETUP                                                                \
    __shared__ float sA[HH * HH];                                               \
    const int lane = threadIdx.x;                                               \
    const int c16  = lane & 15;                                                 \
    const int g    = lane >> 4;                                                 \
    if (lane < HH) {                                                            \
        float rw[HH];                                                           \
        _Pragma("unroll")                                                       \
        for (int k = 0; k < HH; ++k) rw[k] = tlog[lane * HH + k];               \
        float m = rw[0];                                                        \
        _Pragma("unroll")                                                       \
        for (int k = 1; k < HH; ++k) m = fmaxf(m, rw[k]);                       \
        float z = 0.f;                                                          \
        _Pragma("unroll")                                                       \
        for (int k = 0; k < HH; ++k) { rw[k] = __expf(rw[k] - m); z += rw[k]; } \
        float rz = 1.f / z;                                                     \
        _Pragma("unroll")                                                       \
        for (int k = 0; k < HH; ++k) sA[lane * HH + k] = fmaf(rw[k], rz, F_EPS);\
    }                                                                           \
    __syncthreads();                                                            \
    int sig[8];                                                                 \
    _Pragma("unroll")                                                           \
    for (int e = 0; e < 8; ++e) sig[e] = 4 * g + (e & 3) + 16 * (e >> 2);       \
    bf16x8 aHi, aLo;                                                            \
    _Pragma("unroll")                                                           \
    for (int e = 0; e < 8; ++e) {                                               \
        aHi[e] = (short)f2bf(sA[sig[e] * HH + c16]);                            \
        aLo[e] = (short)f2bf(sA[sig[e] * HH + 16 + c16]);                       \
    }                                                                           \
    float mean8[8], ec1v[8], ec0v[8];                                           \
    _Pragma("unroll")                                                           \
    for (int e = 0; e < 8; ++e) {                                               \
        const int st = sig[e];                                                  \
        mean8[e] = emean[st];                                                   \
        float var = __expf(elvar[st]) + F_MINV;                                 \
        ec1v[e] = 0.5f * F_L2E / var;                                           \
        ec0v[e] = -0.5f * __logf(TWO_PI * var) * F_L2E;                         \
    }

// One recurrence step at t = TB_+U_ (slot (TB_+U_)&7 == U_&7 since TB_%8==0).
#define MSTEP(U_, TB_, HEAVY_, RENORM_, CLAMP_)                                 \
    {                                                                           \
        const float o_ = obuf[(U_) & 7];                                        \
        float qv_[8], e2_[8];                                                   \
        _Pragma("unroll")                                                       \
        for (int e = 0; e < 8; ++e) {                                           \
            float d_ = o_ - mean8[e];                                           \
            qv_[e] = fmaf(d_ * d_, -ec1v[e], ec0v[e]);                          \
            e2_[e] = __builtin_amdgcn_exp2f(qv_[e]);                            \
        }                                                                       \
        f32x4 S0_ = __builtin_amdgcn_mfma_f32_16x16x32_bf16(aHi, Bf, Zc, 0,0,0);\
        f32x4 S1_ = __builtin_amdgcn_mfma_f32_16x16x32_bf16(aLo, Bf, Zc, 0,0,0);\
        sc[0] = S0_[0] * e2_[0]; sc[1] = S0_[1] * e2_[1];                       \
        sc[2] = S0_[2] * e2_[2]; sc[3] = S0_[3] * e2_[3];                       \
        sc[4] = S1_[0] * e2_[4]; sc[5] = S1_[1] * e2_[5];                       \
        sc[6] = S1_[2] * e2_[6]; sc[7] = S1_[3] * e2_[7];                       \
        if (HEAVY_) {                                                           \
            f32x4 v0_, v1_;                                                     \
            v0_[0] = (off + qv_[0] + __builtin_amdgcn_logf(S0_[0])) * F_LN2;    \
            v0_[1] = (off + qv_[1] + __builtin_amdgcn_logf(S0_[1])) * F_LN2;    \
            v0_[2] = (off + qv_[2] + __builtin_amdgcn_logf(S0_[2])) * F_LN2;    \
            v0_[3] = (off + qv_[3] + __builtin_amdgcn_logf(S0_[3])) * F_LN2;    \
            v1_[0] = (off + qv_[4] + __builtin_amdgcn_logf(S1_[0])) * F_LN2;    \
            v1_[1] = (off + qv_[5] + __builtin_amdgcn_logf(S1_[1])) * F_LN2;    \
            v1_[2] = (off + qv_[6] + __builtin_amdgcn_logf(S1_[2])) * F_LN2;    \
            v1_[3] = (off + qv_[7] + __builtin_amdgcn_logf(S1_[3])) * F_LN2;    \
            *(f32x4*)(ap + 4 * g)      = v0_;                                   \
            *(f32x4*)(ap + 16 + 4 * g) = v1_;                                   \
            ap += HH;                                                           \
        }                                                                       \
        if (RENORM_) {                                                          \
            float m_ = fmaxf(fmaxf(fmaxf(sc[0], sc[1]), fmaxf(sc[2], sc[3])),   \
                             fmaxf(fmaxf(sc[4], sc[5]), fmaxf(sc[6], sc[7])));  \
            m_ = pmax32(m_); m_ = pmax16(m_);                                   \
            int ee_; frexpf(m_, &ee_);                                          \
            float s_ = ldexpf(1.0f, -ee_);                                      \
            _Pragma("unroll")                                                   \
            for (int e = 0; e < 8; ++e) sc[e] *= s_;                            \
            off += (float)ee_;                                                  \
        }                                                                       \
        {                                                                       \
            union { u32x4 u; bf16x8 h; } cv_;                                   \
            cv_.u[0] = cvtpk(sc[0], sc[1]); cv_.u[1] = cvtpk(sc[2], sc[3]);     \
            cv_.u[2] = cvtpk(sc[4], sc[5]); cv_.u[3] = cvtpk(sc[6], sc[7]);     \
            Bf = cv_.h;                                                         \
        }                                                                       \
        {                                                                       \
            int tr_ = (TB_) + (U_) + 8;                                         \
            if (CLAMP_) tr_ = (tr_ > TT - 1) ? (TT - 1) : tr_;                  \
            obuf[(U_) & 7] = obl[tr_];                                          \
        }                                                                       \
    }

#define MGROUP8(TB_, HEAVY_, CLAMP_)                                            \
    MSTEP(1, TB_, HEAVY_, false, CLAMP_)                                        \
    MSTEP(2, TB_, HEAVY_, false, CLAMP_)                                        \
    MSTEP(3, TB_, HEAVY_, false, CLAMP_)                                        \
    MSTEP(4, TB_, HEAVY_, false, CLAMP_)                                        \
    MSTEP(5, TB_, HEAVY_, false, CLAMP_)                                        \
    MSTEP(6, TB_, HEAVY_, false, CLAMP_)                                        \
    MSTEP(7, TB_, HEAVY_, false, CLAMP_)                                        \
    MSTEP(8, TB_, HEAVY_, true,  CLAMP_)

#define PACK_SC_TO_BF                                                           \
    { union { u32x4 u; bf16x8 h; } cv_;                                         \
      cv_.u[0] = cvtpk(sc[0], sc[1]); cv_.u[1] = cvtpk(sc[2], sc[3]);           \
      cv_.u[2] = cvtpk(sc[4], sc[5]); cv_.u[3] = cvtpk(sc[6], sc[7]);           \
      Bf = cv_.h; }

#define CHAIN_SUM(V_)                                                           \
    float V_ = ((sc[0] + sc[1]) + (sc[2] + sc[3]))                              \
             + ((sc[4] + sc[5]) + (sc[6] + sc[7]));                             \
    V_ = psum32(V_); V_ = psum16(V_);

// ============ kernel 1: warmup + boundary records (no alpha stores) =========
__global__ __launch_bounds__(64, 1)
void hmm_m1(const float* __restrict__ obs,
            const float* __restrict__ tlog,
            const float* __restrict__ ilog,
            const float* __restrict__ emean,
            const float* __restrict__ elvar,
            float* __restrict__ wsf)
{
    MF_SETUP
    const int grp = (int)blockIdx.x & 31;
    const int c   = (int)blockIdx.x >> 5;        // chunk 0..63
    const int b   = grp * 16 + c16;              // this lane's chain
    const float* obl = obs + (size_t)b * TT;
    float* wrec = wsf + ((size_t)b * NCH + c) * RST;
    const int t0 = (c == 0) ? 0 : (c * CL - CW);

    float off = 0.f;
    float sc[8];
    bf16x8 Bf;
    const f32x4 Zc = {0.f, 0.f, 0.f, 0.f};
    float* ap = nullptr; (void)ap;               // unused (HEAVY_=false)
    float obuf[8];

    if (c == 0) {
        // exact init at t=0
        float il2v[8];
        {
            float m = ilog[0];
            #pragma unroll
            for (int k = 1; k < HH; ++k) m = fmaxf(m, ilog[k]);
            float z = 0.f;
            #pragma unroll
            for (int k = 0; k < HH; ++k) z += __expf(ilog[k] - m);
            float rz = 1.f / z;
            #pragma unroll
            for (int e = 0; e < 8; ++e)
                il2v[e] = __log2f(__expf(ilog[sig[e]] - m) * rz + F_EPS);
        }
        float o = obl[0];
        #pragma unroll
        for (int e = 0; e < 8; ++e) {
            float d = o - mean8[e];
            float a2 = il2v[e] + fmaf(d * d, -ec1v[e], ec0v[e]);
            sc[e] = __builtin_amdgcn_exp2f(a2);
        }
        PACK_SC_TO_BF
    } else {
        union { u32x4 u; bf16x8 h; } one_;
        one_.u[0] = 0x3F803F80u; one_.u[1] = 0x3F803F80u;
        one_.u[2] = 0x3F803F80u; one_.u[3] = 0x3F803F80u;
        Bf = one_.h;                              // uniform start
        #pragma unroll
        for (int e = 0; e < 8; ++e) sc[e] = 1.0f;
    }
    #pragma unroll
    for (int m = 1; m <= 8; ++m) obuf[m & 7] = obl[t0 + m];

    if (c > 0) {                                  // warmup CW steps
        for (int j = 0; j < CW / 8; ++j) { MGROUP8(t0 + 8 * j, false, false) }
        // record 1 at boundary t = c*CL: p, lambda_start, l2
        CHAIN_SUM(v)
        float l2 = __builtin_amdgcn_logf(v);
        if (g == 0) { wrec[32] = off + l2; wrec[34] = l2; }
        *(f4*)(wrec + 4 * g)      = (f4){sc[0], sc[1], sc[2], sc[3]};
        *(f4*)(wrec + 16 + 4 * g) = (f4){sc[4], sc[5], sc[6], sc[7]};
    }
    if (c < NCH - 1) {                            // traverse CL steps
        const int tW = c * CL;
        for (int j = 0; j < CL / 8; ++j) { MGROUP8(tW + 8 * j, false, false) }
        CHAIN_SUM(v)
        if (g == 0) wrec[33] = off + __builtin_amdgcn_logf(v);   // lambda_end
    }
}

// ============ kernel 3: corrected re-run, alpha stores, ll ==================
__global__ __launch_bounds__(64, 1)
void hmm_m3(const float* __restrict__ obs,
            const float* __restrict__ tlog,
            const float* __restrict__ ilog,
            const float* __restrict__ emean,
            const float* __restrict__ elvar,
            const float* __restrict__ wsf,
            float* __restrict__ alpha,
            float* __restrict__ ll)
{
    MF_SETUP
    const int grp = (int)blockIdx.x & 31;
    const int c   = (int)blockIdx.x >> 5;
    const int b   = grp * 16 + c16;
    const float* obl = obs + (size_t)b * TT;
    const size_t aBase = (size_t)b * TT * HH;
    const int tS = c * CL;

    float off;
    float sc[8];
    bf16x8 Bf;
    const f32x4 Zc = {0.f, 0.f, 0.f, 0.f};
    float obuf[8];
    float* ap = alpha + aBase + (size_t)(tS + 1) * HH;   // row base; lanes add 4g

    if (c == 0) {
        float il2v[8];
        {
            float m = ilog[0];
            #pragma unroll
            for (int k = 1; k < HH; ++k) m = fmaxf(m, ilog[k]);
            float z = 0.f;
            #pragma unroll
            for (int k = 0; k < HH; ++k) z += __expf(ilog[k] - m);
            float rz = 1.f / z;
            #pragma unroll
            for (int e = 0; e < 8; ++e)
                il2v[e] = __log2f(__expf(ilog[sig[e]] - m) * rz + F_EPS);
        }
        float o = obl[0];
        f32x4 w0, w1;
        #pragma unroll
        for (int e = 0; e < 8; ++e) {
            float d  = o - mean8[e];
            float a2 = il2v[e] + fmaf(d * d, -ec1v[e], ec0v[e]);
            sc[e] = __builtin_amdgcn_exp2f(a2);
            if (e < 4) w0[e] = a2 * F_LN2; else w1[e - 4] = a2 * F_LN2;
        }
        float* a0p = alpha + aBase;               // t = 0 row
        *(f32x4*)(a0p + 4 * g)      = w0;
        *(f32x4*)(a0p + 16 + 4 * g) = w1;
        PACK_SC_TO_BF
        off = 0.f;
    } else {
        const float* wr = wsf + ((size_t)b * NCH + c) * RST;
        f4 r0 = *(const f4*)(wr + 4 * g);
        f4 r1 = *(const f4*)(wr + 16 + 4 * g);
        sc[0] = r0.x; sc[1] = r0.y; sc[2] = r0.z; sc[3] = r0.w;
        sc[4] = r1.x; sc[5] = r1.y; sc[6] = r1.z; sc[7] = r1.w;
        PACK_SC_TO_BF
        const float* wb = wsf + (size_t)b * NCH * RST;
        float T_ = wb[33];                        // true LSE2 at t = CL
        for (int cc = 1; cc < c; ++cc)
            T_ += wb[cc * RST + 33] - wb[cc * RST + 32];
        off = T_ - wr[34];                        // true(c*CL) - local l2
    }
    #pragma unroll
    for (int m = 1; m <= 8; ++m) obuf[m & 7] = obl[tS + m];

    if (c < NCH - 1) {
        for (int j = 0; j < CL / 8; ++j) { MGROUP8(tS + 8 * j, true, true) }
    } else {
        for (int j = 0; j < 7; ++j) { MGROUP8(tS + 8 * j, true, true) }
        // partial group: t = 4089..4095 (7 steps, no trailing renorm)
        MSTEP(1, tS + 56, true, false, true)
        MSTEP(2, tS + 56, true, false, true)
        MSTEP(3, tS + 56, true, false, true)
        MSTEP(4, tS + 56, true, false, true)
        MSTEP(5, tS + 56, true, false, true)
        MSTEP(6, tS + 56, true, false, true)
        MSTEP(7, tS + 56, true, false, true)
        // log-likelihood at t = 4095
        CHAIN_SUM(v)
        if (g == 0) ll[b] = (off + __builtin_amdgcn_logf(v)) * F_LN2;
    }
}

extern "C" void kernel_launch(void* const* d_in, const int* in_sizes, int n_in,
                              void* d_out, int out_size, void* d_ws, size_t ws_size,
                              hipStream_t stream)
{
    const float* obs = (const float*)d_in[0];
    const float* tl  = (const float*)d_in[1];
    const float* il  = (const float*)d_in[2];
    const float* em  = (const float*)d_in[3];
    const float* ev  = (const float*)d_in[4];
    float* alpha = (float*)d_out;
    float* ll    = alpha + (size_t)BB * TT * HH;
    float* wsf   = (float*)d_ws;   // needs BB*NCH*RST*4 = 4.72 MB

    hmm_m1<<<(BB / 16) * NCH, 64, 0, stream>>>(obs, tl, il, em, ev, wsf);
    hmm_m3<<<(BB / 16) * NCH, 64, 0, stream>>>(obs, tl, il, em, ev, wsf, alpha, ll);
}

// Round 16
// 95.155 us; speedup vs baseline: 7.1779x; 1.0807x over previous
//
#include <hip/hip_runtime.h>
#include <cmath>

#define HH 32
#define TT 4096
#define BB 512
#define NCH 64          // chunks per chain
#define CL  64          // chunk length (NCH*CL == TT)
#define CW  32          // warmup steps (multiple of 8; t0 stays 0 mod 8)
#define RST 36          // ws floats per (chain,chunk) record (144 B)

typedef float  f4     __attribute__((ext_vector_type(4)));
typedef float  f32x4  __attribute__((ext_vector_type(4)));
typedef short  bf16x8 __attribute__((ext_vector_type(8)));
typedef unsigned int u32x4 __attribute__((ext_vector_type(4)));

constexpr float F_EPS  = 1e-10f;
constexpr float F_MINV = 1e-6f;
constexpr float F_L2E  = 1.44269504088896340736f;   // log2(e)
constexpr float F_LN2  = 0.69314718055994530942f;   // ln(2)
constexpr float TWO_PI = 6.28318530717958647693f;

// ---- pair-combine with ^16/^32 partner (verified r8-r13): same value into
// both operands -> {own, partner} in some order -> sum/max unconditional.
#if __has_builtin(__builtin_amdgcn_permlane16_swap)
__device__ __forceinline__ float psum16(float a) {
    auto rr = __builtin_amdgcn_permlane16_swap(__float_as_uint(a), __float_as_uint(a), false, false);
    return __uint_as_float(rr[0]) + __uint_as_float(rr[1]);
}
__device__ __forceinline__ float pmax16(float a) {
    auto rr = __builtin_amdgcn_permlane16_swap(__float_as_uint(a), __float_as_uint(a), false, false);
    return fmaxf(__uint_as_float(rr[0]), __uint_as_float(rr[1]));
}
#else
__device__ __forceinline__ float psum16(float a) {
    float x, y;
    asm volatile("v_mov_b32 %0, %2\n\tv_mov_b32 %1, %2\n\tv_permlane16_swap_b32 %0, %1"
                 : "=&v"(x), "=&v"(y) : "v"(a));
    return x + y;
}
__device__ __forceinline__ float pmax16(float a) {
    float x, y;
    asm volatile("v_mov_b32 %0, %2\n\tv_mov_b32 %1, %2\n\tv_permlane16_swap_b32 %0, %1"
                 : "=&v"(x), "=&v"(y) : "v"(a));
    return fmaxf(x, y);
}
#endif
#if __has_builtin(__builtin_amdgcn_permlane32_swap)
__device__ __forceinline__ float psum32(float a) {
    auto rr = __builtin_amdgcn_permlane32_swap(__float_as_uint(a), __float_as_uint(a), false, false);
    return __uint_as_float(rr[0]) + __uint_as_float(rr[1]);
}
__device__ __forceinline__ float pmax32(float a) {
    auto rr = __builtin_amdgcn_permlane32_swap(__float_as_uint(a), __float_as_uint(a), false, false);
    return fmaxf(__uint_as_float(rr[0]), __uint_as_float(rr[1]));
}
#else
__device__ __forceinline__ float psum32(float a) {
    float x, y;
    asm volatile("v_mov_b32 %0, %2\n\tv_mov_b32 %1, %2\n\tv_permlane32_swap_b32 %0, %1"
                 : "=&v"(x), "=&v"(y) : "v"(a));
    return x + y;
}
__device__ __forceinline__ float pmax32(float a) {
    float x, y;
    asm volatile("v_mov_b32 %0, %2\n\tv_mov_b32 %1, %2\n\tv_permlane32_swap_b32 %0, %1"
                 : "=&v"(x), "=&v"(y) : "v"(a));
    return fmaxf(x, y);
}
#endif

__device__ __forceinline__ unsigned short f2bf(float f) {   // RNE f32->bf16
    unsigned u = __float_as_uint(f);
    return (unsigned short)((u + 0x7FFFu + ((u >> 16) & 1u)) >> 16);
}
__device__ __forceinline__ unsigned cvtpk(float lo, float hi) {
    unsigned r;
    asm("v_cvt_pk_bf16_f32 %0, %1, %2" : "=v"(r) : "v"(lo), "v"(hi));
    return r;
}

// Per-lane setup (verified r13). Lane l: chain-col c16=l&15, quarter g=l>>4.
// sig[e]=4g+(e&3)+16(e>>2) is both the D-fragment row set AND the B-operand
// k-slots (sigma folded into A' columns) -> D feeds B with zero shuffles.
#define MF_SETUP                                                                \
    __shared__ float sA[HH * HH];                                               \
    const int lane = threadIdx.x;                                               \
    const int c16  = lane & 15;                                                 \
    const int g    = lane >> 4;                                                 \
    if (lane < HH) {                                                            \
        float rw[HH];                                                           \
        _Pragma("unroll")                                                       \
        for (int k = 0; k < HH; ++k) rw[k] = tlog[lane * HH + k];               \
        float m = rw[0];                                                        \
        _Pragma("unroll")                                                       \
        for (int k = 1; k < HH; ++k) m = fmaxf(m, rw[k]);                       \
        float z = 0.f;                                                          \
        _Pragma("unroll")                                                       \
        for (int k = 0; k < HH; ++k) { rw[k] = __expf(rw[k] - m); z += rw[k]; } \
        float rz = 1.f / z;                                                     \
        _Pragma("unroll")                                                       \
        for (int k = 0; k < HH; ++k) sA[lane * HH + k] = fmaf(rw[k], rz, F_EPS);\
    }                                                                           \
    __syncthreads();                                                            \
    int sig[8];                                                                 \
    _Pragma("unroll")                                                           \
    for (int e = 0; e < 8; ++e) sig[e] = 4 * g + (e & 3) + 16 * (e >> 2);       \
    bf16x8 aHi, aLo;                                                            \
    _Pragma("unroll")                                                           \
    for (int e = 0; e < 8; ++e) {                                               \
        aHi[e] = (short)f2bf(sA[sig[e] * HH + c16]);                            \
        aLo[e] = (short)f2bf(sA[sig[e] * HH + 16 + c16]);                       \
    }                                                                           \
    float mean8[8], ec1v[8], ec0v[8];                                           \
    _Pragma("unroll")                                                           \
    for (int e = 0; e < 8; ++e) {                                               \
        const int st = sig[e];                                                  \
        mean8[e] = emean[st];                                                   \
        float var = __expf(elvar[st]) + F_MINV;                                 \
        ec1v[e] = 0.5f * F_L2E / var;                                           \
        ec0v[e] = -0.5f * __logf(TWO_PI * var) * F_L2E;                         \
    }

// One recurrence step at t = TB_+U_ (slot (TB_+U_)&7 == U_&7 since TB_%8==0).
#define MSTEP(U_, TB_, HEAVY_, RENORM_, CLAMP_)                                 \
    {                                                                           \
        const float o_ = obuf[(U_) & 7];                                        \
        float qv_[8], e2_[8];                                                   \
        _Pragma("unroll")                                                       \
        for (int e = 0; e < 8; ++e) {                                           \
            float d_ = o_ - mean8[e];                                           \
            qv_[e] = fmaf(d_ * d_, -ec1v[e], ec0v[e]);                          \
            e2_[e] = __builtin_amdgcn_exp2f(qv_[e]);                            \
        }                                                                       \
        f32x4 S0_ = __builtin_amdgcn_mfma_f32_16x16x32_bf16(aHi, Bf, Zc, 0,0,0);\
        f32x4 S1_ = __builtin_amdgcn_mfma_f32_16x16x32_bf16(aLo, Bf, Zc, 0,0,0);\
        sc[0] = S0_[0] * e2_[0]; sc[1] = S0_[1] * e2_[1];                       \
        sc[2] = S0_[2] * e2_[2]; sc[3] = S0_[3] * e2_[3];                       \
        sc[4] = S1_[0] * e2_[4]; sc[5] = S1_[1] * e2_[5];                       \
        sc[6] = S1_[2] * e2_[6]; sc[7] = S1_[3] * e2_[7];                       \
        if (HEAVY_) {                                                           \
            f32x4 v0_, v1_;                                                     \
            v0_[0] = (off + qv_[0] + __builtin_amdgcn_logf(S0_[0])) * F_LN2;    \
            v0_[1] = (off + qv_[1] + __builtin_amdgcn_logf(S0_[1])) * F_LN2;    \
            v0_[2] = (off + qv_[2] + __builtin_amdgcn_logf(S0_[2])) * F_LN2;    \
            v0_[3] = (off + qv_[3] + __builtin_amdgcn_logf(S0_[3])) * F_LN2;    \
            v1_[0] = (off + qv_[4] + __builtin_amdgcn_logf(S1_[0])) * F_LN2;    \
            v1_[1] = (off + qv_[5] + __builtin_amdgcn_logf(S1_[1])) * F_LN2;    \
            v1_[2] = (off + qv_[6] + __builtin_amdgcn_logf(S1_[2])) * F_LN2;    \
            v1_[3] = (off + qv_[7] + __builtin_amdgcn_logf(S1_[3])) * F_LN2;    \
            *(f32x4*)(ap + 4 * g)      = v0_;                                   \
            *(f32x4*)(ap + 16 + 4 * g) = v1_;                                   \
            ap += HH;                                                           \
        }                                                                       \
        if (RENORM_) {                                                          \
            float m_ = fmaxf(fmaxf(fmaxf(sc[0], sc[1]), fmaxf(sc[2], sc[3])),   \
                             fmaxf(fmaxf(sc[4], sc[5]), fmaxf(sc[6], sc[7])));  \
            m_ = pmax32(m_); m_ = pmax16(m_);                                   \
            int ee_; frexpf(m_, &ee_);                                          \
            float s_ = ldexpf(1.0f, -ee_);                                      \
            _Pragma("unroll")                                                   \
            for (int e = 0; e < 8; ++e) sc[e] *= s_;                            \
            off += (float)ee_;                                                  \
        }                                                                       \
        {                                                                       \
            union { u32x4 u; bf16x8 h; } cv_;                                   \
            cv_.u[0] = cvtpk(sc[0], sc[1]); cv_.u[1] = cvtpk(sc[2], sc[3]);     \
            cv_.u[2] = cvtpk(sc[4], sc[5]); cv_.u[3] = cvtpk(sc[6], sc[7]);     \
            Bf = cv_.h;                                                         \
        }                                                                       \
        {                                                                       \
            int tr_ = (TB_) + (U_) + 8;                                         \
            if (CLAMP_) tr_ = (tr_ > TT - 1) ? (TT - 1) : tr_;                  \
            obuf[(U_) & 7] = obl[tr_];                                          \
        }                                                                       \
    }

#define MGROUP8(TB_, HEAVY_, CLAMP_)                                            \
    MSTEP(1, TB_, HEAVY_, false, CLAMP_)                                        \
    MSTEP(2, TB_, HEAVY_, false, CLAMP_)                                        \
    MSTEP(3, TB_, HEAVY_, false, CLAMP_)                                        \
    MSTEP(4, TB_, HEAVY_, false, CLAMP_)                                        \
    MSTEP(5, TB_, HEAVY_, false, CLAMP_)                                        \
    MSTEP(6, TB_, HEAVY_, false, CLAMP_)                                        \
    MSTEP(7, TB_, HEAVY_, false, CLAMP_)                                        \
    MSTEP(8, TB_, HEAVY_, true,  CLAMP_)

#define PACK_SC_TO_BF                                                           \
    { union { u32x4 u; bf16x8 h; } cv_;                                         \
      cv_.u[0] = cvtpk(sc[0], sc[1]); cv_.u[1] = cvtpk(sc[2], sc[3]);           \
      cv_.u[2] = cvtpk(sc[4], sc[5]); cv_.u[3] = cvtpk(sc[6], sc[7]);           \
      Bf = cv_.h; }

#define CHAIN_SUM(V_)                                                           \
    float V_ = ((sc[0] + sc[1]) + (sc[2] + sc[3]))                              \
             + ((sc[4] + sc[5]) + (sc[6] + sc[7]));                             \
    V_ = psum32(V_); V_ = psum16(V_);

// ============ kernel 1: warmup + boundary records (no alpha stores) =========
__global__ __launch_bounds__(64, 1)
void hmm_m1(const float* __restrict__ obs,
            const float* __restrict__ tlog,
            const float* __restrict__ ilog,
            const float* __restrict__ emean,
            const float* __restrict__ elvar,
            float* __restrict__ wsf)
{
    MF_SETUP
    const int grp = (int)blockIdx.x & 31;
    const int c   = (int)blockIdx.x >> 5;        // chunk 0..63
    const int b   = grp * 16 + c16;              // this lane's chain
    const float* obl = obs + (size_t)b * TT;
    float* wrec = wsf + ((size_t)b * NCH + c) * RST;
    const int t0 = (c == 0) ? 0 : (c * CL - CW);

    float off = 0.f;
    float sc[8];
    bf16x8 Bf;
    const f32x4 Zc = {0.f, 0.f, 0.f, 0.f};
    float* ap = nullptr; (void)ap;               // unused (HEAVY_=false)
    float obuf[8];

    if (c == 0) {
        // exact init at t=0
        float il2v[8];
        {
            float m = ilog[0];
            #pragma unroll
            for (int k = 1; k < HH; ++k) m = fmaxf(m, ilog[k]);
            float z = 0.f;
            #pragma unroll
            for (int k = 0; k < HH; ++k) z += __expf(ilog[k] - m);
            float rz = 1.f / z;
            #pragma unroll
            for (int e = 0; e < 8; ++e)
                il2v[e] = __log2f(__expf(ilog[sig[e]] - m) * rz + F_EPS);
        }
        float o = obl[0];
        #pragma unroll
        for (int e = 0; e < 8; ++e) {
            float d = o - mean8[e];
            float a2 = il2v[e] + fmaf(d * d, -ec1v[e], ec0v[e]);
            sc[e] = __builtin_amdgcn_exp2f(a2);
        }
        PACK_SC_TO_BF
    } else {
        union { u32x4 u; bf16x8 h; } one_;
        one_.u[0] = 0x3F803F80u; one_.u[1] = 0x3F803F80u;
        one_.u[2] = 0x3F803F80u; one_.u[3] = 0x3F803F80u;
        Bf = one_.h;                              // uniform start
        #pragma unroll
        for (int e = 0; e < 8; ++e) sc[e] = 1.0f;
    }
    #pragma unroll
    for (int m = 1; m <= 8; ++m) obuf[m & 7] = obl[t0 + m];

    if (c > 0) {                                  // warmup CW steps
        for (int j = 0; j < CW / 8; ++j) { MGROUP8(t0 + 8 * j, false, false) }
        // record 1 at boundary t = c*CL: p, lambda_start, l2
        CHAIN_SUM(v)
        float l2 = __builtin_amdgcn_logf(v);
        if (g == 0) { wrec[32] = off + l2; wrec[34] = l2; }
        *(f4*)(wrec + 4 * g)      = (f4){sc[0], sc[1], sc[2], sc[3]};
        *(f4*)(wrec + 16 + 4 * g) = (f4){sc[4], sc[5], sc[6], sc[7]};
    }
    if (c < NCH - 1) {                            // traverse CL steps
        const int tW = c * CL;
        for (int j = 0; j < CL / 8; ++j) { MGROUP8(tW + 8 * j, false, false) }
        CHAIN_SUM(v)
        if (g == 0) wrec[33] = off + __builtin_amdgcn_logf(v);   // lambda_end
    }
}

// ============ kernel 3: corrected re-run, alpha stores, ll ==================
__global__ __launch_bounds__(64, 1)
void hmm_m3(const float* __restrict__ obs,
            const float* __restrict__ tlog,
            const float* __restrict__ ilog,
            const float* __restrict__ emean,
            const float* __restrict__ elvar,
            const float* __restrict__ wsf,
            float* __restrict__ alpha,
            float* __restrict__ ll)
{
    MF_SETUP
    const int grp = (int)blockIdx.x & 31;
    const int c   = (int)blockIdx.x >> 5;
    const int b   = grp * 16 + c16;
    const float* obl = obs + (size_t)b * TT;
    const size_t aBase = (size_t)b * TT * HH;
    const int tS = c * CL;

    float off;
    float sc[8];
    bf16x8 Bf;
    const f32x4 Zc = {0.f, 0.f, 0.f, 0.f};
    float obuf[8];
    float* ap = alpha + aBase + (size_t)(tS + 1) * HH;   // row base; lanes add 4g

    if (c == 0) {
        float il2v[8];
        {
            float m = ilog[0];
            #pragma unroll
            for (int k = 1; k < HH; ++k) m = fmaxf(m, ilog[k]);
            float z = 0.f;
            #pragma unroll
            for (int k = 0; k < HH; ++k) z += __expf(ilog[k] - m);
            float rz = 1.f / z;
            #pragma unroll
            for (int e = 0; e < 8; ++e)
                il2v[e] = __log2f(__expf(ilog[sig[e]] - m) * rz + F_EPS);
        }
        float o = obl[0];
        f32x4 w0, w1;
        #pragma unroll
        for (int e = 0; e < 8; ++e) {
            float d  = o - mean8[e];
            float a2 = il2v[e] + fmaf(d * d, -ec1v[e], ec0v[e]);
            sc[e] = __builtin_amdgcn_exp2f(a2);
            if (e < 4) w0[e] = a2 * F_LN2; else w1[e - 4] = a2 * F_LN2;
        }
        float* a0p = alpha + aBase;               // t = 0 row
        *(f32x4*)(a0p + 4 * g)      = w0;
        *(f32x4*)(a0p + 16 + 4 * g) = w1;
        PACK_SC_TO_BF
        off = 0.f;
    } else {
        const float* wr = wsf + ((size_t)b * NCH + c) * RST;
        f4 r0 = *(const f4*)(wr + 4 * g);
        f4 r1 = *(const f4*)(wr + 16 + 4 * g);
        sc[0] = r0.x; sc[1] = r0.y; sc[2] = r0.z; sc[3] = r0.w;
        sc[4] = r1.x; sc[5] = r1.y; sc[6] = r1.z; sc[7] = r1.w;
        PACK_SC_TO_BF
        const float* wb = wsf + (size_t)b * NCH * RST;
        float T_ = wb[33];                        // true LSE2 at t = CL
        for (int cc = 1; cc < c; ++cc)
            T_ += wb[cc * RST + 33] - wb[cc * RST + 32];
        off = T_ - wr[34];                        // true(c*CL) - local l2
    }
    #pragma unroll
    for (int m = 1; m <= 8; ++m) obuf[m & 7] = obl[tS + m];

    if (c < NCH - 1) {
        for (int j = 0; j < CL / 8; ++j) { MGROUP8(tS + 8 * j, true, true) }
    } else {
        for (int j = 0; j < 7; ++j) { MGROUP8(tS + 8 * j, true, true) }
        // partial group: t = 4089..4095 (7 steps, no trailing renorm)
        MSTEP(1, tS + 56, true, false, true)
        MSTEP(2, tS + 56, true, false, true)
        MSTEP(3, tS + 56, true, false, true)
        MSTEP(4, tS + 56, true, false, true)
        MSTEP(5, tS + 56, true, false, true)
        MSTEP(6, tS + 56, true, false, true)
        MSTEP(7, tS + 56, true, false, true)
        // log-likelihood at t = 4095
        CHAIN_SUM(v)
        if (g == 0) ll[b] = (off + __builtin_amdgcn_logf(v)) * F_LN2;
    }
}

extern "C" void kernel_launch(void* const* d_in, const int* in_sizes, int n_in,
                              void* d_out, int out_size, void* d_ws, size_t ws_size,
                              hipStream_t stream)
{
    const float* obs = (const float*)d_in[0];
    const float* tl  = (const float*)d_in[1];
    const float* il  = (const float*)d_in[2];
    const float* em  = (const float*)d_in[3];
    const float* ev  = (const float*)d_in[4];
    float* alpha = (float*)d_out;
    float* ll    = alpha + (size_t)BB * TT * HH;
    float* wsf   = (float*)d_ws;   // needs BB*NCH*RST*4 = 4.72 MB

    hmm_m1<<<(BB / 16) * NCH, 64, 0, stream>>>(obs, tl, il, em, ev, wsf);
    hmm_m3<<<(BB / 16) * NCH, 64, 0, stream>>>(obs, tl, il, em, ev, wsf, alpha, ll);
}